// Round 5
// baseline (1213.836 us; speedup 1.0000x reference)
//
#include <hip/hip_runtime.h>

// ---------------------------------------------------------------------------
// Transformer_16784732193201 — round 5
// Changes vs r4: REVERT gemm_ln fusion (occupancy collapse, 9.5%). New
// row-panel GEMM (gemm_rp): BM=64, A staged ONCE in LDS (swizzled, 1 barrier),
// B fragments read directly from global (L2-resident weights), full N per
// block in 256-col chunks. Split ln/bn kernels restored; addpos_ln kept.
// ws layout:
//   xbuf  fp32 [82944,256]               @ 0          (84,934,656 B)
//   bufA  bf16 [82944,256]               @ 84934656   (42,467,328 B)
//   bufB  bf16 [82944,768]               @ 127401984  (127,401,984 B)
//   weights bf16 + fused bias            @ 254803968  (~3.2 MB)
// ---------------------------------------------------------------------------

typedef __attribute__((ext_vector_type(4))) float f32x4;
typedef __attribute__((ext_vector_type(8))) short s16x8;
typedef __attribute__((ext_vector_type(4))) unsigned short u16x4;
typedef __attribute__((ext_vector_type(8))) unsigned short u16x8;

__device__ __forceinline__ float bf2f(unsigned short u) {
  unsigned int v = ((unsigned int)u) << 16;
  return __builtin_bit_cast(float, v);
}
__device__ __forceinline__ unsigned short f2bf(float f) {
  unsigned int u = __builtin_bit_cast(unsigned int, f);
  u += 0x7fffu + ((u >> 16) & 1u);
  return (unsigned short)(u >> 16);
}

#define GLD16(gp, lp)                                                       \
  __builtin_amdgcn_global_load_lds(                                         \
      (const __attribute__((address_space(1))) void*)(gp),                  \
      (__attribute__((address_space(3))) void*)(lp), 16, 0, 0)

// ---------------------------------------------------------------------------
// Row-panel GEMM: C[m,n] = sum_k A[m,k]*W[n,k] + bias (+epilogue).
// BM=64 rows/block; A [64][KC-half=256] staged once in LDS (XOR-swizzled via
// pre-swizzled global source); W fragments loaded per-k from global (L2-hot).
// 4 waves each own 64 cols of a 256-col chunk; NCHUNK chunks cover N.
// KC=512 (NCHUNK must be 1) stages A in two 256-halves.
// EPI: 0 bias->bf16 ; 1 bias+relu->bf16 ; 2 bias+resid->f32 ; 3 bias->f32
//      (EPI 3 clamps W rows to nW for the 51-wide conv).
// ---------------------------------------------------------------------------
template <int KC, int NCHUNK, int EPI>
__global__ __launch_bounds__(256) void gemm_rp(
    const unsigned short* __restrict__ A, const unsigned short* __restrict__ W,
    const float* __restrict__ bias, const float* __restrict__ resid,
    void* __restrict__ Cout, int ldc, int n_valid, int nW) {
  __shared__ unsigned short Alds[64 * 256];  // 32 KB
  const int tid = threadIdx.x, wave = tid >> 6, lane = tid & 63;
  const int nwg = gridDim.x;
  const int swz = (blockIdx.x & 7) * (nwg >> 3) + (blockIdx.x >> 3);
  const int row0 = swz * 64;
  const int fr = lane & 15, g4 = lane >> 4;

  // stage A half h: 32 x 1KB wave-issues; source col pre-swizzled (rule 21)
  auto stageA = [&](int h) {
#pragma unroll
    for (int j = 0; j < 8; ++j) {
      int idx = wave * 8 + j;                // 1KB chunk id, 0..31
      int r = idx * 2 + (lane >> 5);         // local row 0..63
      int cs = ((lane & 31) ^ (r & 7)) * 8;  // swizzled col (shorts)
      const unsigned short* src = A + (size_t)(row0 + r) * KC + h * 256 + cs;
      GLD16(src, &Alds[idx * 512]);
    }
  };

  auto compute = [&](f32x4(&acc)[4][4], int c, int h) {
#pragma unroll
    for (int k = 0; k < 8; ++k) {
      s16x8 bfr[4];
#pragma unroll
      for (int j = 0; j < 4; ++j) {
        int br = c * 256 + wave * 64 + j * 16 + fr;
        if constexpr (EPI == 3) {
          if (br >= nW) br = nW - 1;
        }
        bfr[j] = *(const s16x8*)(W + (size_t)br * KC + h * 256 + k * 32 + g4 * 8);
      }
      s16x8 af[4];
#pragma unroll
      for (int i = 0; i < 4; ++i) {
        int R = i * 16 + fr;
        af[i] = *(const s16x8*)&Alds[R * 256 + (((k * 4 + g4) ^ (R & 7)) * 8)];
      }
#pragma unroll
      for (int i = 0; i < 4; ++i)
#pragma unroll
        for (int j = 0; j < 4; ++j)
          acc[i][j] =
              __builtin_amdgcn_mfma_f32_16x16x32_bf16(af[i], bfr[j], acc[i][j], 0, 0, 0);
    }
  };

  stageA(0);
  __syncthreads();

#pragma unroll
  for (int c = 0; c < NCHUNK; ++c) {
    f32x4 acc[4][4];
#pragma unroll
    for (int i = 0; i < 4; ++i)
#pragma unroll
      for (int j = 0; j < 4; ++j) acc[i][j] = (f32x4)0.f;

    compute(acc, c, 0);
    if constexpr (KC == 512) {
      __syncthreads();
      stageA(1);
      __syncthreads();
      compute(acc, c, 1);
    }

    // epilogue: D mapping col=lane&15, row=(lane>>4)*4+r
#pragma unroll
    for (int j = 0; j < 4; ++j) {
      int col = c * 256 + wave * 64 + j * 16 + fr;
      if (col < n_valid) {
        float bv = bias[col];
#pragma unroll
        for (int i = 0; i < 4; ++i) {
#pragma unroll
          for (int r = 0; r < 4; ++r) {
            int row = row0 + i * 16 + g4 * 4 + r;
            float v = acc[i][j][r] + bv;
            if constexpr (EPI == 1) v = fmaxf(v, 0.f);
            size_t idx = (size_t)row * ldc + col;
            if constexpr (EPI == 2) {
              ((float*)Cout)[idx] = v + resid[idx];
            } else if constexpr (EPI == 3) {
              ((float*)Cout)[idx] = v;
            } else {
              ((unsigned short*)Cout)[idx] = f2bf(v);
            }
          }
        }
      }
    }
  }
}

// ---------------------------------------------------------------------------
// LayerNorm: unbiased var (D-1), out = a*(x-mean)/(sqrt(var)+1e-6)+b -> bf16
// ---------------------------------------------------------------------------
__global__ __launch_bounds__(256) void ln_kernel(const float* __restrict__ x,
                                                 const float* __restrict__ a,
                                                 const float* __restrict__ b,
                                                 unsigned short* __restrict__ out) {
  const int wave = threadIdx.x >> 6, lane = threadIdx.x & 63;
  const size_t row = (size_t)blockIdx.x * 4 + wave;
  const float* xr = x + row * 256;
  f32x4 v = *(const f32x4*)(xr + lane * 4);
  float s = v[0] + v[1] + v[2] + v[3];
#pragma unroll
  for (int off = 32; off >= 1; off >>= 1) s += __shfl_xor(s, off);
  float mean = s * (1.f / 256.f);
  f32x4 d = v - mean;
  float sq = d[0] * d[0] + d[1] * d[1] + d[2] * d[2] + d[3] * d[3];
#pragma unroll
  for (int off = 32; off >= 1; off >>= 1) sq += __shfl_xor(sq, off);
  float var = sq * (1.f / 255.f);
  float scl = 1.f / (sqrtf(var) + 1e-6f);
  f32x4 av = *(const f32x4*)(a + lane * 4);
  f32x4 bv = *(const f32x4*)(b + lane * 4);
  u16x4 ob;
#pragma unroll
  for (int j = 0; j < 4; ++j) ob[j] = f2bf(av[j] * d[j] * scl + bv[j]);
  *(u16x4*)(out + row * 256 + lane * 4) = ob;
}

// ---------------------------------------------------------------------------
// Fused x+pos -> xbuf (fp32) and LayerNorm -> bufA (bf16). 1 wave per row.
// ---------------------------------------------------------------------------
__global__ __launch_bounds__(256) void addpos_ln(const f32x4* __restrict__ x,
                                                 const f32x4* __restrict__ pos,
                                                 const float* __restrict__ a,
                                                 const float* __restrict__ b,
                                                 f32x4* __restrict__ xout,
                                                 unsigned short* __restrict__ lnout) {
  const int wave = threadIdx.x >> 6, lane = threadIdx.x & 63;
  const size_t row = (size_t)blockIdx.x * 4 + wave;
  f32x4 v = x[row * 64 + lane] + pos[(row % 81) * 64 + lane];
  xout[row * 64 + lane] = v;
  float s = v[0] + v[1] + v[2] + v[3];
#pragma unroll
  for (int off = 32; off >= 1; off >>= 1) s += __shfl_xor(s, off);
  float mean = s * (1.f / 256.f);
  f32x4 d = v - mean;
  float sq = d[0] * d[0] + d[1] * d[1] + d[2] * d[2] + d[3] * d[3];
#pragma unroll
  for (int off = 32; off >= 1; off >>= 1) sq += __shfl_xor(sq, off);
  float var = sq * (1.f / 255.f);
  float scl = 1.f / (sqrtf(var) + 1e-6f);
  f32x4 av = *(const f32x4*)(a + lane * 4);
  f32x4 bv = *(const f32x4*)(b + lane * 4);
  u16x4 ob;
#pragma unroll
  for (int j = 0; j < 4; ++j) ob[j] = f2bf(av[j] * d[j] * scl + bv[j]);
  *(u16x4*)(lnout + row * 256 + lane * 4) = ob;
}

// ---------------------------------------------------------------------------
// MFMA strided sparse attention. 1 wave = 1 stream (b,h,m); 4 waves/block.
// ---------------------------------------------------------------------------
__global__ __launch_bounds__(256) void attn_mfma(const unsigned short* __restrict__ qkv,
                                                 unsigned short* __restrict__ o) {
  constexpr int LS = 40;  // LDS row stride in shorts
  const int wave = threadIdx.x >> 6, lane = threadIdx.x & 63;
  const int sid = blockIdx.x * 4 + wave;
  const int m = sid % 3, hh = (sid / 3) & 7, b = sid / 24;
  __shared__ unsigned short VtS[4][32 * LS];
  __shared__ unsigned short PlS[4][32 * LS];
  unsigned short* vt = VtS[wave];
  unsigned short* pl = PlS[wave];

  const unsigned short* base = qkv + (size_t)b * 81 * 768 + (size_t)m * 768 + hh * 32;
  const int fr = lane & 15;
  const int ko = (lane >> 4) * 8;
  const int g4 = lane >> 4;

  s16x8 qf[2], kf[2];
#pragma unroll
  for (int i = 0; i < 2; ++i) {
    int g = fr + 16 * i;
    if (g > 26) g = 26;
    const unsigned short* qp = base + (size_t)g * 2304 + ko;
    qf[i] = *(const s16x8*)qp;
    kf[i] = *(const s16x8*)(qp + 256);
  }

#pragma unroll
  for (int it = 0; it < 2; ++it) {
    int slot = it * 64 + lane;
    int g = slot >> 2, s = slot & 3;
    if (g < 27) {
      u16x8 v = *(const u16x8*)(base + (size_t)g * 2304 + 512 + s * 8);
#pragma unroll
      for (int j = 0; j < 8; ++j) vt[(s * 8 + j) * LS + g] = v[j];
    } else {
#pragma unroll
      for (int j = 0; j < 8; ++j) vt[(s * 8 + j) * LS + g] = 0;
    }
  }

  f32x4 sacc[2][2];
#pragma unroll
  for (int i = 0; i < 2; ++i)
#pragma unroll
    for (int j = 0; j < 2; ++j) sacc[i][j] = (f32x4)0.f;
#pragma unroll
  for (int i = 0; i < 2; ++i)
#pragma unroll
    for (int j = 0; j < 2; ++j)
      sacc[i][j] = __builtin_amdgcn_mfma_f32_16x16x32_bf16(qf[i], kf[j], sacc[i][j], 0, 0, 0);

  const float scale = 0.17677669529663687f;  // 1/sqrt(32)
  const bool v1 = fr < 11;
#pragma unroll
  for (int i = 0; i < 2; ++i) {
#pragma unroll
    for (int r = 0; r < 4; ++r) {
      float a0 = sacc[i][0][r] * scale;
      float a1 = v1 ? sacc[i][1][r] * scale : -3.0e38f;
      float mx = fmaxf(a0, a1);
#pragma unroll
      for (int off = 1; off <= 8; off <<= 1) mx = fmaxf(mx, __shfl_xor(mx, off));
      float e0 = __expf(a0 - mx);
      float e1 = v1 ? __expf(a1 - mx) : 0.f;
      float sm = e0 + e1;
#pragma unroll
      for (int off = 1; off <= 8; off <<= 1) sm += __shfl_xor(sm, off);
      float inv = 1.f / sm;
      int row = i * 16 + 4 * g4 + r;
      pl[row * LS + fr] = f2bf(e0 * inv);
      pl[row * LS + 16 + fr] = f2bf(e1 * inv);
    }
  }
  __syncthreads();

  s16x8 pf[2], vf[2];
#pragma unroll
  for (int i = 0; i < 2; ++i) pf[i] = *(const s16x8*)&pl[(fr + 16 * i) * LS + ko];
#pragma unroll
  for (int j = 0; j < 2; ++j) vf[j] = *(const s16x8*)&vt[(fr + 16 * j) * LS + ko];

  f32x4 oacc[2][2];
#pragma unroll
  for (int i = 0; i < 2; ++i)
#pragma unroll
    for (int j = 0; j < 2; ++j) oacc[i][j] = (f32x4)0.f;
#pragma unroll
  for (int i = 0; i < 2; ++i)
#pragma unroll
    for (int j = 0; j < 2; ++j)
      oacc[i][j] = __builtin_amdgcn_mfma_f32_16x16x32_bf16(pf[i], vf[j], oacc[i][j], 0, 0, 0);

  __syncthreads();
#pragma unroll
  for (int i = 0; i < 2; ++i)
#pragma unroll
    for (int j = 0; j < 2; ++j)
#pragma unroll
      for (int r = 0; r < 4; ++r)
        vt[(i * 16 + 4 * g4 + r) * LS + j * 16 + fr] = f2bf(oacc[i][j][r]);
  __syncthreads();

#pragma unroll
  for (int it = 0; it < 2; ++it) {
    int slot = it * 64 + lane;
    int g = slot >> 2, s = slot & 3;
    if (g < 27) {
      u16x8 v = *(const u16x8*)&vt[g * LS + s * 8];
      *(u16x8*)(o + (size_t)(b * 81 + m + 3 * g) * 256 + hh * 32 + s * 8) = v;
    }
  }
}

// eval BatchNorm (mean0/var1) fused cast: xn = x/sqrt(1+1e-5)*g + b -> bf16
__global__ __launch_bounds__(256) void bn_kernel(const float* __restrict__ x,
                                                 const float* __restrict__ g,
                                                 const float* __restrict__ bb,
                                                 unsigned short* __restrict__ out) {
  int i = blockIdx.x * 256 + threadIdx.x;  // float4 index
  f32x4 v = ((const f32x4*)x)[i];
  int c = (i << 2) & 255;
  f32x4 gv = *(const f32x4*)(g + c);
  f32x4 bv = *(const f32x4*)(bb + c);
  const float is = 0.9999950000374997f;  // 1/sqrt(1.00001)
  u16x4 o;
#pragma unroll
  for (int j = 0; j < 4; ++j) o[j] = f2bf(v[j] * is * gv[j] + bv[j]);
  ((u16x4*)out)[i] = o;
}

__global__ __launch_bounds__(256) void cvt_kernel(const f32x4* __restrict__ src,
                                                  u16x4* __restrict__ dst, int n4) {
  int i = blockIdx.x * 256 + threadIdx.x;
  if (i < n4) {
    f32x4 v = src[i];
    u16x4 o;
#pragma unroll
    for (int j = 0; j < 4; ++j) o[j] = f2bf(v[j]);
    dst[i] = o;
  }
}

// pack Wq|Wk|Wv -> wqkv3 bf16 [3][768][256]
__global__ __launch_bounds__(256) void qkvpack_kernel(const float* __restrict__ Wq,
                                                      const float* __restrict__ Wk,
                                                      const float* __restrict__ Wv,
                                                      u16x4* __restrict__ dst) {
  int i4 = blockIdx.x * 256 + threadIdx.x;
  int e = i4 * 4;
  int l = e / 196608;
  int r = (e / 256) % 768;
  int c = e & 255;
  const float* src;
  if (r < 256) src = Wq + (size_t)l * 65536 + r * 256 + c;
  else if (r < 512) src = Wk + (size_t)l * 65536 + (r - 256) * 256 + c;
  else src = Wv + (size_t)l * 65536 + (r - 512) * 256 + c;
  f32x4 v = *(const f32x4*)src;
  u16x4 o;
#pragma unroll
  for (int j = 0; j < 4; ++j) o[j] = f2bf(v[j]);
  dst[i4] = o;
}

__global__ __launch_bounds__(256) void biaspack_kernel(const float* __restrict__ bq,
                                                       const float* __restrict__ bk,
                                                       const float* __restrict__ bv,
                                                       float* __restrict__ dst) {
  int i = blockIdx.x * 256 + threadIdx.x;
  if (i >= 2304) return;
  int l = i / 768, r = i % 768;
  float v = (r < 256) ? bq[l * 256 + r] : (r < 512) ? bk[l * 256 + r - 256]
                                                    : bv[l * 256 + r - 512];
  dst[i] = v;
}

extern "C" void kernel_launch(void* const* d_in, const int* in_sizes, int n_in,
                              void* d_out, int out_size, void* d_ws, size_t ws_size,
                              hipStream_t stream) {
  const float* x      = (const float*)d_in[0];
  const float* pos    = (const float*)d_in[1];
  const float* ln1_a  = (const float*)d_in[2];
  const float* ln1_b  = (const float*)d_in[3];
  const float* Wq     = (const float*)d_in[4];
  const float* bq     = (const float*)d_in[5];
  const float* Wk     = (const float*)d_in[6];
  const float* bk     = (const float*)d_in[7];
  const float* Wv     = (const float*)d_in[8];
  const float* bv     = (const float*)d_in[9];
  const float* Wo     = (const float*)d_in[10];
  const float* bo     = (const float*)d_in[11];
  const float* ln2_a  = (const float*)d_in[12];
  const float* ln2_b  = (const float*)d_in[13];
  const float* W1     = (const float*)d_in[14];
  const float* b1     = (const float*)d_in[15];
  const float* W2     = (const float*)d_in[16];
  const float* b2     = (const float*)d_in[17];
  const float* bn_g   = (const float*)d_in[18];
  const float* bn_b   = (const float*)d_in[19];
  const float* conv_w = (const float*)d_in[20];
  const float* conv_b = (const float*)d_in[21];

  char* ws = (char*)d_ws;
  float* xbuf = (float*)ws;
  unsigned short* bufA = (unsigned short*)(ws + 84934656);
  unsigned short* bufB = (unsigned short*)(ws + 127401984);
  unsigned short* wqkv3 = (unsigned short*)(ws + 254803968);
  unsigned short* wo3 = wqkv3 + 589824;
  unsigned short* w13 = wo3 + 196608;
  unsigned short* w23 = w13 + 393216;
  unsigned short* cw  = w23 + 393216;
  float* qkvb3 = (float*)(ws + 254803968 + 3171840);

  auto cvt = [&](const float* s, unsigned short* d, int n) {
    int n4 = n / 4;
    cvt_kernel<<<(n4 + 255) / 256, 256, 0, stream>>>((const f32x4*)s, (u16x4*)d, n4);
  };
  qkvpack_kernel<<<576, 256, 0, stream>>>(Wq, Wk, Wv, (u16x4*)wqkv3);
  biaspack_kernel<<<9, 256, 0, stream>>>(bq, bk, bv, qkvb3);
  cvt(Wo, wo3, 196608);
  cvt(W1, w13, 393216);
  cvt(W2, w23, 393216);
  cvt(conv_w, cw, 13056);

  // x+pos -> xbuf ; LN1(layer0) -> bufA
  addpos_ln<<<20736, 256, 0, stream>>>((const f32x4*)x, (const f32x4*)pos, ln1_a, ln1_b,
                                       (f32x4*)xbuf, bufA);

  for (int l = 0; l < 3; ++l) {
    // fused QKV -> bufB [BT,768]
    gemm_rp<256, 3, 0><<<1296, 256, 0, stream>>>(bufA, wqkv3 + l * 196608,
                                                 qkvb3 + l * 768, nullptr, (void*)bufB,
                                                 768, 768, 768);
    attn_mfma<<<6144, 256, 0, stream>>>(bufB, bufA);
    // O-proj + residual -> xbuf
    gemm_rp<256, 1, 2><<<1296, 256, 0, stream>>>(bufA, wo3 + l * 65536, bo + l * 256,
                                                 xbuf, (void*)xbuf, 256, 256, 256);
    ln_kernel<<<20736, 256, 0, stream>>>(xbuf, ln2_a + l * 256, ln2_b + l * 256, bufA);
    // FFN1 (relu) -> bufB [BT,512]
    gemm_rp<256, 2, 1><<<1296, 256, 0, stream>>>(bufA, w13 + l * 131072, b1 + l * 512,
                                                 nullptr, (void*)bufB, 512, 512, 512);
    // FFN2 + residual -> xbuf
    gemm_rp<512, 1, 2><<<1296, 256, 0, stream>>>(bufB, w23 + l * 131072, b2 + l * 256,
                                                 xbuf, (void*)xbuf, 256, 256, 256);
    if (l < 2)
      ln_kernel<<<20736, 256, 0, stream>>>(xbuf, ln1_a + (l + 1) * 256,
                                           ln1_b + (l + 1) * 256, bufA);
  }
  bn_kernel<<<20736, 256, 0, stream>>>(xbuf, bn_g, bn_b, bufA);
  gemm_rp<256, 1, 3><<<1296, 256, 0, stream>>>(bufA, cw, conv_b, nullptr, d_out, 51, 51,
                                               51);
}

// Round 6
// 936.237 us; speedup vs baseline: 1.2965x; 1.2965x over previous
//
#include <hip/hip_runtime.h>

// ---------------------------------------------------------------------------
// Transformer_16784732193201 — round 6
// = round 3 structure (best so far, 934us) + double-buffered 2-phase K-loop:
//   prologue stage(buf0); loop { barrier; stage(next into buf^1); compute(cur) }
//   Staging latency now hides under MFMA/ds_read instead of being barrier-
//   exposed twice per K-step. LDS 64KB (2 blocks/CU, same as r3 measured).
// ws layout:
//   xbuf  fp32 [82944,256]               @ 0          (84,934,656 B)
//   bufA  bf16 [82944,256]               @ 84934656   (42,467,328 B)
//   bufB  bf16 [82944,768]               @ 127401984  (127,401,984 B)
//   weights bf16 + fused bias            @ 254803968  (~3.2 MB)
// ---------------------------------------------------------------------------

typedef __attribute__((ext_vector_type(4))) float f32x4;
typedef __attribute__((ext_vector_type(8))) short s16x8;
typedef __attribute__((ext_vector_type(4))) unsigned short u16x4;
typedef __attribute__((ext_vector_type(8))) unsigned short u16x8;

__device__ __forceinline__ float bf2f(unsigned short u) {
  unsigned int v = ((unsigned int)u) << 16;
  return __builtin_bit_cast(float, v);
}
__device__ __forceinline__ unsigned short f2bf(float f) {
  unsigned int u = __builtin_bit_cast(unsigned int, f);
  u += 0x7fffu + ((u >> 16) & 1u);
  return (unsigned short)(u >> 16);
}

#define GLD16(gp, lp)                                                       \
  __builtin_amdgcn_global_load_lds(                                         \
      (const __attribute__((address_space(1))) void*)(gp),                  \
      (__attribute__((address_space(3))) void*)(lp), 16, 0, 0)

// ---------------------------------------------------------------------------
// Generic bf16 GEMM:  C[m,n] = sum_k A[m,k] * W[n,k]  (+bias, epilogue)
// EPI: 0 = bias -> bf16 ; 1 = bias+relu -> bf16 ; 2 = bias+residual -> f32 ;
//      3 = bias -> f32 (clamped W rows for the 51-wide conv)
// BM=128, BK=64, 4 waves as 2x2. T2 XOR-swizzled LDS (pre-swizzled source);
// XCD-bijective 1-D grid, y-fastest; DOUBLE-BUFFERED 2-phase K-loop.
// ---------------------------------------------------------------------------
template <int BN, int EPI, int NY>
__global__ __launch_bounds__(256) void gemm_bt(
    const unsigned short* __restrict__ A, const unsigned short* __restrict__ W,
    const float* __restrict__ bias, const float* __restrict__ resid,
    void* __restrict__ Cout, int K, int ldc, int n_valid, int nW) {
  constexpr int BM = 128, BK = 64;
  constexpr int WN = BN / 2;
  constexpr int FM = 4, FN = WN / 16;
  __shared__ unsigned short smem[2][(BM + BN) * BK];  // A tile then B tile

  const int tid = threadIdx.x, wave = tid >> 6, lane = tid & 63;
  const int nwg = gridDim.x;
  const int swz = (blockIdx.x & 7) * (nwg >> 3) + (blockIdx.x >> 3);
  const int row0 = (swz / NY) * BM, ncol0 = (swz % NY) * BN;
  const int wr = wave >> 1, wc = wave & 1;
  const int fr = lane & 15, g4 = lane >> 4, ko = g4 * 8;
  const int swr = (fr & 7) << 3;          // read-side XOR (shorts)
  const int l8 = lane >> 3;
  const int lkS = ((lane & 7) ^ l8) * 8;  // pre-swizzled source col (shorts)

  f32x4 acc[FM][FN];
#pragma unroll
  for (int i = 0; i < FM; ++i)
#pragma unroll
    for (int j = 0; j < FN; ++j) acc[i][j] = (f32x4)0.f;

  auto stage = [&](int b, int kt) {
#pragma unroll
    for (int j = 0; j < 4; ++j) {
      int ci = wave * 4 + j;
      const unsigned short* src = A + (size_t)(row0 + ci * 8 + l8) * K + kt * BK + lkS;
      GLD16(src, &smem[b][ci * 512]);
    }
#pragma unroll
    for (int j = 0; j < BN / 32; ++j) {
      int ci = wave * (BN / 32) + j;
      int brow = ncol0 + ci * 8 + l8;
      if (brow >= nW) brow = nW - 1;
      const unsigned short* src = W + (size_t)brow * K + kt * BK + lkS;
      GLD16(src, &smem[b][BM * BK + ci * 512]);
    }
  };

  const int nkt = K / BK;
  stage(0, 0);
  int cur = 0;
  for (int kt = 0; kt < nkt; ++kt) {
    __syncthreads();  // drains stage(cur) [+ prev compute's lgkm]
    if (kt + 1 < nkt) stage(cur ^ 1, kt + 1);
    const unsigned short* Al = smem[cur];
    const unsigned short* Bl = smem[cur] + BM * BK;
#pragma unroll
    for (int kk = 0; kk < 2; ++kk) {
      s16x8 af[FM], bfr[FN];
#pragma unroll
      for (int i = 0; i < FM; ++i)
        af[i] = *(const s16x8*)&Al[(wr * 64 + i * 16 + fr) * BK + ((kk * 32 + ko) ^ swr)];
#pragma unroll
      for (int j = 0; j < FN; ++j)
        bfr[j] = *(const s16x8*)&Bl[(wc * WN + j * 16 + fr) * BK + ((kk * 32 + ko) ^ swr)];
#pragma unroll
      for (int i = 0; i < FM; ++i)
#pragma unroll
        for (int j = 0; j < FN; ++j)
          acc[i][j] =
              __builtin_amdgcn_mfma_f32_16x16x32_bf16(af[i], bfr[j], acc[i][j], 0, 0, 0);
    }
    cur ^= 1;
  }

  // epilogue: D mapping col=lane&15, row=(lane>>4)*4+r
  const int cr = g4 * 4, cc = lane & 15;
#pragma unroll
  for (int i = 0; i < FM; ++i) {
#pragma unroll
    for (int j = 0; j < FN; ++j) {
      int col = ncol0 + wc * WN + j * 16 + cc;
      if (col >= n_valid) continue;
      float bv = bias[col];
#pragma unroll
      for (int r = 0; r < 4; ++r) {
        int row = row0 + wr * 64 + i * 16 + cr + r;
        float v = acc[i][j][r] + bv;
        if constexpr (EPI == 1) v = fmaxf(v, 0.f);
        size_t idx = (size_t)row * ldc + col;
        if constexpr (EPI == 2) {
          ((float*)Cout)[idx] = v + resid[idx];
        } else if constexpr (EPI == 3) {
          ((float*)Cout)[idx] = v;
        } else {
          ((unsigned short*)Cout)[idx] = f2bf(v);
        }
      }
    }
  }
}

// ---------------------------------------------------------------------------
// LayerNorm: unbiased var (D-1), out = a*(x-mean)/(sqrt(var)+1e-6)+b -> bf16
// ---------------------------------------------------------------------------
__global__ __launch_bounds__(256) void ln_kernel(const float* __restrict__ x,
                                                 const float* __restrict__ a,
                                                 const float* __restrict__ b,
                                                 unsigned short* __restrict__ out) {
  const int wave = threadIdx.x >> 6, lane = threadIdx.x & 63;
  const size_t row = (size_t)blockIdx.x * 4 + wave;
  const float* xr = x + row * 256;
  f32x4 v = *(const f32x4*)(xr + lane * 4);
  float s = v[0] + v[1] + v[2] + v[3];
#pragma unroll
  for (int off = 32; off >= 1; off >>= 1) s += __shfl_xor(s, off);
  float mean = s * (1.f / 256.f);
  f32x4 d = v - mean;
  float sq = d[0] * d[0] + d[1] * d[1] + d[2] * d[2] + d[3] * d[3];
#pragma unroll
  for (int off = 32; off >= 1; off >>= 1) sq += __shfl_xor(sq, off);
  float var = sq * (1.f / 255.f);
  float scl = 1.f / (sqrtf(var) + 1e-6f);
  f32x4 av = *(const f32x4*)(a + lane * 4);
  f32x4 bv = *(const f32x4*)(b + lane * 4);
  u16x4 ob;
#pragma unroll
  for (int j = 0; j < 4; ++j) ob[j] = f2bf(av[j] * d[j] * scl + bv[j]);
  *(u16x4*)(out + row * 256 + lane * 4) = ob;
}

// ---------------------------------------------------------------------------
// Fused x+pos -> xbuf (fp32) and LayerNorm -> bufA (bf16). 1 wave per row.
// ---------------------------------------------------------------------------
__global__ __launch_bounds__(256) void addpos_ln(const f32x4* __restrict__ x,
                                                 const f32x4* __restrict__ pos,
                                                 const float* __restrict__ a,
                                                 const float* __restrict__ b,
                                                 f32x4* __restrict__ xout,
                                                 unsigned short* __restrict__ lnout) {
  const int wave = threadIdx.x >> 6, lane = threadIdx.x & 63;
  const size_t row = (size_t)blockIdx.x * 4 + wave;
  f32x4 v = x[row * 64 + lane] + pos[(row % 81) * 64 + lane];
  xout[row * 64 + lane] = v;
  float s = v[0] + v[1] + v[2] + v[3];
#pragma unroll
  for (int off = 32; off >= 1; off >>= 1) s += __shfl_xor(s, off);
  float mean = s * (1.f / 256.f);
  f32x4 d = v - mean;
  float sq = d[0] * d[0] + d[1] * d[1] + d[2] * d[2] + d[3] * d[3];
#pragma unroll
  for (int off = 32; off >= 1; off >>= 1) sq += __shfl_xor(sq, off);
  float var = sq * (1.f / 255.f);
  float scl = 1.f / (sqrtf(var) + 1e-6f);
  f32x4 av = *(const f32x4*)(a + lane * 4);
  f32x4 bv = *(const f32x4*)(b + lane * 4);
  u16x4 ob;
#pragma unroll
  for (int j = 0; j < 4; ++j) ob[j] = f2bf(av[j] * d[j] * scl + bv[j]);
  *(u16x4*)(lnout + row * 256 + lane * 4) = ob;
}

// ---------------------------------------------------------------------------
// MFMA strided sparse attention. 1 wave = 1 stream (b,h,m); 4 waves/block.
// ---------------------------------------------------------------------------
__global__ __launch_bounds__(256) void attn_mfma(const unsigned short* __restrict__ qkv,
                                                 unsigned short* __restrict__ o) {
  constexpr int LS = 40;  // LDS row stride in shorts
  const int wave = threadIdx.x >> 6, lane = threadIdx.x & 63;
  const int sid = blockIdx.x * 4 + wave;
  const int m = sid % 3, hh = (sid / 3) & 7, b = sid / 24;
  __shared__ unsigned short VtS[4][32 * LS];
  __shared__ unsigned short PlS[4][32 * LS];
  unsigned short* vt = VtS[wave];
  unsigned short* pl = PlS[wave];

  const unsigned short* base = qkv + (size_t)b * 81 * 768 + (size_t)m * 768 + hh * 32;
  const int fr = lane & 15;
  const int ko = (lane >> 4) * 8;
  const int g4 = lane >> 4;

  s16x8 qf[2], kf[2];
#pragma unroll
  for (int i = 0; i < 2; ++i) {
    int g = fr + 16 * i;
    if (g > 26) g = 26;
    const unsigned short* qp = base + (size_t)g * 2304 + ko;
    qf[i] = *(const s16x8*)qp;
    kf[i] = *(const s16x8*)(qp + 256);
  }

#pragma unroll
  for (int it = 0; it < 2; ++it) {
    int slot = it * 64 + lane;
    int g = slot >> 2, s = slot & 3;
    if (g < 27) {
      u16x8 v = *(const u16x8*)(base + (size_t)g * 2304 + 512 + s * 8);
#pragma unroll
      for (int j = 0; j < 8; ++j) vt[(s * 8 + j) * LS + g] = v[j];
    } else {
#pragma unroll
      for (int j = 0; j < 8; ++j) vt[(s * 8 + j) * LS + g] = 0;
    }
  }

  f32x4 sacc[2][2];
#pragma unroll
  for (int i = 0; i < 2; ++i)
#pragma unroll
    for (int j = 0; j < 2; ++j) sacc[i][j] = (f32x4)0.f;
#pragma unroll
  for (int i = 0; i < 2; ++i)
#pragma unroll
    for (int j = 0; j < 2; ++j)
      sacc[i][j] = __builtin_amdgcn_mfma_f32_16x16x32_bf16(qf[i], kf[j], sacc[i][j], 0, 0, 0);

  const float scale = 0.17677669529663687f;  // 1/sqrt(32)
  const bool v1 = fr < 11;
#pragma unroll
  for (int i = 0; i < 2; ++i) {
#pragma unroll
    for (int r = 0; r < 4; ++r) {
      float a0 = sacc[i][0][r] * scale;
      float a1 = v1 ? sacc[i][1][r] * scale : -3.0e38f;
      float mx = fmaxf(a0, a1);
#pragma unroll
      for (int off = 1; off <= 8; off <<= 1) mx = fmaxf(mx, __shfl_xor(mx, off));
      float e0 = __expf(a0 - mx);
      float e1 = v1 ? __expf(a1 - mx) : 0.f;
      float sm = e0 + e1;
#pragma unroll
      for (int off = 1; off <= 8; off <<= 1) sm += __shfl_xor(sm, off);
      float inv = 1.f / sm;
      int row = i * 16 + 4 * g4 + r;
      pl[row * LS + fr] = f2bf(e0 * inv);
      pl[row * LS + 16 + fr] = f2bf(e1 * inv);
    }
  }
  __syncthreads();

  s16x8 pf[2], vf[2];
#pragma unroll
  for (int i = 0; i < 2; ++i) pf[i] = *(const s16x8*)&pl[(fr + 16 * i) * LS + ko];
#pragma unroll
  for (int j = 0; j < 2; ++j) vf[j] = *(const s16x8*)&vt[(fr + 16 * j) * LS + ko];

  f32x4 oacc[2][2];
#pragma unroll
  for (int i = 0; i < 2; ++i)
#pragma unroll
    for (int j = 0; j < 2; ++j) oacc[i][j] = (f32x4)0.f;
#pragma unroll
  for (int i = 0; i < 2; ++i)
#pragma unroll
    for (int j = 0; j < 2; ++j)
      oacc[i][j] = __builtin_amdgcn_mfma_f32_16x16x32_bf16(pf[i], vf[j], oacc[i][j], 0, 0, 0);

  __syncthreads();
#pragma unroll
  for (int i = 0; i < 2; ++i)
#pragma unroll
    for (int j = 0; j < 2; ++j)
#pragma unroll
      for (int r = 0; r < 4; ++r)
        vt[(i * 16 + 4 * g4 + r) * LS + j * 16 + fr] = f2bf(oacc[i][j][r]);
  __syncthreads();

#pragma unroll
  for (int it = 0; it < 2; ++it) {
    int slot = it * 64 + lane;
    int g = slot >> 2, s = slot & 3;
    if (g < 27) {
      u16x8 v = *(const u16x8*)&vt[g * LS + s * 8];
      *(u16x8*)(o + (size_t)(b * 81 + m + 3 * g) * 256 + hh * 32 + s * 8) = v;
    }
  }
}

// eval BatchNorm (mean0/var1) fused cast: xn = x/sqrt(1+1e-5)*g + b -> bf16
__global__ __launch_bounds__(256) void bn_kernel(const float* __restrict__ x,
                                                 const float* __restrict__ g,
                                                 const float* __restrict__ bb,
                                                 unsigned short* __restrict__ out) {
  int i = blockIdx.x * 256 + threadIdx.x;  // float4 index
  f32x4 v = ((const f32x4*)x)[i];
  int c = (i << 2) & 255;
  f32x4 gv = *(const f32x4*)(g + c);
  f32x4 bv = *(const f32x4*)(bb + c);
  const float is = 0.9999950000374997f;  // 1/sqrt(1.00001)
  u16x4 o;
#pragma unroll
  for (int j = 0; j < 4; ++j) o[j] = f2bf(v[j] * is * gv[j] + bv[j]);
  ((u16x4*)out)[i] = o;
}

__global__ __launch_bounds__(256) void cvt_kernel(const f32x4* __restrict__ src,
                                                  u16x4* __restrict__ dst, int n4) {
  int i = blockIdx.x * 256 + threadIdx.x;
  if (i < n4) {
    f32x4 v = src[i];
    u16x4 o;
#pragma unroll
    for (int j = 0; j < 4; ++j) o[j] = f2bf(v[j]);
    dst[i] = o;
  }
}

// pack Wq|Wk|Wv -> wqkv3 bf16 [3][768][256]
__global__ __launch_bounds__(256) void qkvpack_kernel(const float* __restrict__ Wq,
                                                      const float* __restrict__ Wk,
                                                      const float* __restrict__ Wv,
                                                      u16x4* __restrict__ dst) {
  int i4 = blockIdx.x * 256 + threadIdx.x;
  int e = i4 * 4;
  int l = e / 196608;
  int r = (e / 256) % 768;
  int c = e & 255;
  const float* src;
  if (r < 256) src = Wq + (size_t)l * 65536 + r * 256 + c;
  else if (r < 512) src = Wk + (size_t)l * 65536 + (r - 256) * 256 + c;
  else src = Wv + (size_t)l * 65536 + (r - 512) * 256 + c;
  f32x4 v = *(const f32x4*)src;
  u16x4 o;
#pragma unroll
  for (int j = 0; j < 4; ++j) o[j] = f2bf(v[j]);
  dst[i4] = o;
}

__global__ __launch_bounds__(256) void biaspack_kernel(const float* __restrict__ bq,
                                                       const float* __restrict__ bk,
                                                       const float* __restrict__ bv,
                                                       float* __restrict__ dst) {
  int i = blockIdx.x * 256 + threadIdx.x;
  if (i >= 2304) return;
  int l = i / 768, r = i % 768;
  float v = (r < 256) ? bq[l * 256 + r] : (r < 512) ? bk[l * 256 + r - 256]
                                                    : bv[l * 256 + r - 512];
  dst[i] = v;
}

extern "C" void kernel_launch(void* const* d_in, const int* in_sizes, int n_in,
                              void* d_out, int out_size, void* d_ws, size_t ws_size,
                              hipStream_t stream) {
  const float* x      = (const float*)d_in[0];
  const float* pos    = (const float*)d_in[1];
  const float* ln1_a  = (const float*)d_in[2];
  const float* ln1_b  = (const float*)d_in[3];
  const float* Wq     = (const float*)d_in[4];
  const float* bq     = (const float*)d_in[5];
  const float* Wk     = (const float*)d_in[6];
  const float* bk     = (const float*)d_in[7];
  const float* Wv     = (const float*)d_in[8];
  const float* bv     = (const float*)d_in[9];
  const float* Wo     = (const float*)d_in[10];
  const float* bo     = (const float*)d_in[11];
  const float* ln2_a  = (const float*)d_in[12];
  const float* ln2_b  = (const float*)d_in[13];
  const float* W1     = (const float*)d_in[14];
  const float* b1     = (const float*)d_in[15];
  const float* W2     = (const float*)d_in[16];
  const float* b2     = (const float*)d_in[17];
  const float* bn_g   = (const float*)d_in[18];
  const float* bn_b   = (const float*)d_in[19];
  const float* conv_w = (const float*)d_in[20];
  const float* conv_b = (const float*)d_in[21];

  char* ws = (char*)d_ws;
  float* xbuf = (float*)ws;
  unsigned short* bufA = (unsigned short*)(ws + 84934656);
  unsigned short* bufB = (unsigned short*)(ws + 127401984);
  unsigned short* wqkv3 = (unsigned short*)(ws + 254803968);
  unsigned short* wo3 = wqkv3 + 589824;
  unsigned short* w13 = wo3 + 196608;
  unsigned short* w23 = w13 + 393216;
  unsigned short* cw  = w23 + 393216;
  float* qkvb3 = (float*)(ws + 254803968 + 3171840);

  auto cvt = [&](const float* s, unsigned short* d, int n) {
    int n4 = n / 4;
    cvt_kernel<<<(n4 + 255) / 256, 256, 0, stream>>>((const f32x4*)s, (u16x4*)d, n4);
  };
  qkvpack_kernel<<<576, 256, 0, stream>>>(Wq, Wk, Wv, (u16x4*)wqkv3);
  biaspack_kernel<<<9, 256, 0, stream>>>(bq, bk, bv, qkvb3);
  cvt(Wo, wo3, 196608);
  cvt(W1, w13, 393216);
  cvt(W2, w23, 393216);
  cvt(conv_w, cw, 13056);

  // x+pos -> xbuf ; LN1(layer0) -> bufA
  addpos_ln<<<20736, 256, 0, stream>>>((const f32x4*)x, (const f32x4*)pos, ln1_a, ln1_b,
                                       (f32x4*)xbuf, bufA);

  for (int l = 0; l < 3; ++l) {
    // fused QKV: one GEMM into [BT,768]
    gemm_bt<128, 0, 6><<<3888, 256, 0, stream>>>(bufA, wqkv3 + l * 196608,
                                                 qkvb3 + l * 768, nullptr, (void*)bufB,
                                                 256, 768, 768, 768);
    attn_mfma<<<6144, 256, 0, stream>>>(bufB, bufA);
    // O-proj + residual -> xbuf
    gemm_bt<128, 2, 2><<<1296, 256, 0, stream>>>(bufA, wo3 + l * 65536, bo + l * 256,
                                                 xbuf, (void*)xbuf, 256, 256, 256, 256);
    ln_kernel<<<20736, 256, 0, stream>>>(xbuf, ln2_a + l * 256, ln2_b + l * 256, bufA);
    gemm_bt<128, 1, 4><<<2592, 256, 0, stream>>>(bufA, w13 + l * 131072, b1 + l * 512,
                                                 nullptr, (void*)bufB, 256, 512, 512, 512);
    gemm_bt<128, 2, 2><<<1296, 256, 0, stream>>>(bufB, w23 + l * 131072, b2 + l * 256,
                                                 xbuf, (void*)xbuf, 512, 256, 256, 256);
    if (l < 2)
      ln_kernel<<<20736, 256, 0, stream>>>(xbuf, ln1_a + (l + 1) * 256,
                                           ln1_b + (l + 1) * 256, bufA);
  }
  bn_kernel<<<20736, 256, 0, stream>>>(xbuf, bn_g, bn_b, bufA);
  gemm_bt<64, 3, 1><<<648, 256, 0, stream>>>(bufA, cw, conv_b, nullptr, d_out, 256, 51,
                                             51, 51);
}

// Round 7
// 899.786 us; speedup vs baseline: 1.3490x; 1.0405x over previous
//
#include <hip/hip_runtime.h>

// ---------------------------------------------------------------------------
// Transformer_16784732193201 — round 7
// vs r6: (a) QKV via 8-wave BM=128xBN=256 single-buffered GEMM (gemm8);
// (b) LN2 fused into FFN1 *prologue* (row-LN while staging A to LDS; K-loop
//     then stages only B); (c) BatchNorm fused into conv prologue;
// (d) O-proj/FFN2 back to r3 single-buffered gemm_bt (proven best).
// ws layout:
//   xbuf  fp32 [82944,256]               @ 0
//   bufA  bf16 [82944,256]               @ 84934656
//   bufB  bf16 [82944,768]               @ 127401984
//   weights bf16 + fused bias            @ 254803968
// ---------------------------------------------------------------------------

typedef __attribute__((ext_vector_type(4))) float f32x4;
typedef __attribute__((ext_vector_type(8))) short s16x8;
typedef __attribute__((ext_vector_type(4))) unsigned short u16x4;
typedef __attribute__((ext_vector_type(8))) unsigned short u16x8;

__device__ __forceinline__ float bf2f(unsigned short u) {
  unsigned int v = ((unsigned int)u) << 16;
  return __builtin_bit_cast(float, v);
}
__device__ __forceinline__ unsigned short f2bf(float f) {
  unsigned int u = __builtin_bit_cast(unsigned int, f);
  u += 0x7fffu + ((u >> 16) & 1u);
  return (unsigned short)(u >> 16);
}

#define GLD16(gp, lp)                                                       \
  __builtin_amdgcn_global_load_lds(                                         \
      (const __attribute__((address_space(1))) void*)(gp),                  \
      (__attribute__((address_space(3))) void*)(lp), 16, 0, 0)

// ---------------------------------------------------------------------------
// 8-wave GEMM: BM=128, BN=256, 512 threads (2x4 waves), single-buffer 48KB.
// EPI 0: bias -> bf16 ; EPI 2: bias + resid -> fp32.
// ---------------------------------------------------------------------------
template <int EPI, int NY>
__global__ __launch_bounds__(512) void gemm8(
    const unsigned short* __restrict__ A, const unsigned short* __restrict__ W,
    const float* __restrict__ bias, const float* __restrict__ resid,
    void* __restrict__ Cout, int K, int ldc) {
  __shared__ unsigned short Alds[128 * 64];  // 16 KB
  __shared__ unsigned short Blds[256 * 64];  // 32 KB
  const int tid = threadIdx.x, wave = tid >> 6, lane = tid & 63;
  const int nwg = gridDim.x;
  const int swz = (blockIdx.x & 7) * (nwg >> 3) + (blockIdx.x >> 3);
  const int row0 = (swz / NY) * 128, ncol0 = (swz % NY) * 256;
  const int wr = wave >> 2, wc = wave & 3;
  const int fr = lane & 15, g4 = lane >> 4, ko = g4 * 8;
  const int swr = (fr & 7) << 3;
  const int l8 = lane >> 3;
  const int lkS = ((lane & 7) ^ l8) * 8;

  f32x4 acc[4][4];
#pragma unroll
  for (int i = 0; i < 4; ++i)
#pragma unroll
    for (int j = 0; j < 4; ++j) acc[i][j] = (f32x4)0.f;

  const int nkt = K / 64;
  for (int kt = 0; kt < nkt; ++kt) {
    __syncthreads();
#pragma unroll
    for (int j = 0; j < 2; ++j) {  // A: 16 chunks of 1KB
      int ci = wave * 2 + j;
      const unsigned short* src = A + (size_t)(row0 + ci * 8 + l8) * K + kt * 64 + lkS;
      GLD16(src, &Alds[ci * 512]);
    }
#pragma unroll
    for (int j = 0; j < 4; ++j) {  // B: 32 chunks
      int ci = wave * 4 + j;
      const unsigned short* src = W + (size_t)(ncol0 + ci * 8 + l8) * K + kt * 64 + lkS;
      GLD16(src, &Blds[ci * 512]);
    }
    __syncthreads();
#pragma unroll
    for (int kk = 0; kk < 2; ++kk) {
      s16x8 af[4], bfr[4];
#pragma unroll
      for (int i = 0; i < 4; ++i)
        af[i] = *(const s16x8*)&Alds[(wr * 64 + i * 16 + fr) * 64 + ((kk * 32 + ko) ^ swr)];
#pragma unroll
      for (int j = 0; j < 4; ++j)
        bfr[j] = *(const s16x8*)&Blds[(wc * 64 + j * 16 + fr) * 64 + ((kk * 32 + ko) ^ swr)];
#pragma unroll
      for (int i = 0; i < 4; ++i)
#pragma unroll
        for (int j = 0; j < 4; ++j)
          acc[i][j] =
              __builtin_amdgcn_mfma_f32_16x16x32_bf16(af[i], bfr[j], acc[i][j], 0, 0, 0);
    }
  }

  const int cr = g4 * 4;
#pragma unroll
  for (int i = 0; i < 4; ++i) {
#pragma unroll
    for (int j = 0; j < 4; ++j) {
      int col = ncol0 + wc * 64 + j * 16 + fr;
      float bv = bias[col];
#pragma unroll
      for (int r = 0; r < 4; ++r) {
        int row = row0 + wr * 64 + i * 16 + cr + r;
        float v = acc[i][j][r] + bv;
        size_t idx = (size_t)row * ldc + col;
        if constexpr (EPI == 2) {
          ((float*)Cout)[idx] = v + resid[idx];
        } else {
          ((unsigned short*)Cout)[idx] = f2bf(v);
        }
      }
    }
  }
}

// ---------------------------------------------------------------------------
// r3-proven generic GEMM (single-buffered): used for O-proj and FFN2 (EPI 2).
// ---------------------------------------------------------------------------
template <int BN, int EPI, int NY>
__global__ __launch_bounds__(256) void gemm_bt(
    const unsigned short* __restrict__ A, const unsigned short* __restrict__ W,
    const float* __restrict__ bias, const float* __restrict__ resid,
    void* __restrict__ Cout, int K, int ldc) {
  constexpr int BM = 128, BK = 64;
  constexpr int WN = BN / 2;
  constexpr int FM = 4, FN = WN / 16;
  __shared__ unsigned short Alds[BM * BK];
  __shared__ unsigned short Blds[BN * BK];

  const int tid = threadIdx.x, wave = tid >> 6, lane = tid & 63;
  const int nwg = gridDim.x;
  const int swz = (blockIdx.x & 7) * (nwg >> 3) + (blockIdx.x >> 3);
  const int row0 = (swz / NY) * BM, ncol0 = (swz % NY) * BN;
  const int wr = wave >> 1, wc = wave & 1;
  const int fr = lane & 15, g4 = lane >> 4, ko = g4 * 8;
  const int swr = (fr & 7) << 3;
  const int l8 = lane >> 3;
  const int lkS = ((lane & 7) ^ l8) * 8;

  f32x4 acc[FM][FN];
#pragma unroll
  for (int i = 0; i < FM; ++i)
#pragma unroll
    for (int j = 0; j < FN; ++j) acc[i][j] = (f32x4)0.f;

  const int nkt = K / BK;
  for (int kt = 0; kt < nkt; ++kt) {
    __syncthreads();
#pragma unroll
    for (int j = 0; j < 4; ++j) {
      int ci = wave * 4 + j;
      const unsigned short* src = A + (size_t)(row0 + ci * 8 + l8) * K + kt * BK + lkS;
      GLD16(src, &Alds[ci * 512]);
    }
#pragma unroll
    for (int j = 0; j < BN / 32; ++j) {
      int ci = wave * (BN / 32) + j;
      const unsigned short* src =
          W + (size_t)(ncol0 + ci * 8 + l8) * K + kt * BK + lkS;
      GLD16(src, &Blds[ci * 512]);
    }
    __syncthreads();
#pragma unroll
    for (int kk = 0; kk < 2; ++kk) {
      s16x8 af[FM], bfr[FN];
#pragma unroll
      for (int i = 0; i < FM; ++i)
        af[i] = *(const s16x8*)&Alds[(wr * 64 + i * 16 + fr) * BK + ((kk * 32 + ko) ^ swr)];
#pragma unroll
      for (int j = 0; j < FN; ++j)
        bfr[j] = *(const s16x8*)&Blds[(wc * WN + j * 16 + fr) * BK + ((kk * 32 + ko) ^ swr)];
#pragma unroll
      for (int i = 0; i < FM; ++i)
#pragma unroll
        for (int j = 0; j < FN; ++j)
          acc[i][j] =
              __builtin_amdgcn_mfma_f32_16x16x32_bf16(af[i], bfr[j], acc[i][j], 0, 0, 0);
    }
  }

  const int cr = g4 * 4;
#pragma unroll
  for (int i = 0; i < FM; ++i) {
#pragma unroll
    for (int j = 0; j < FN; ++j) {
      int col = ncol0 + wc * WN + j * 16 + fr;
      float bv = bias[col];
#pragma unroll
      for (int r = 0; r < 4; ++r) {
        int row = row0 + wr * 64 + i * 16 + cr + r;
        float v = acc[i][j][r] + bv;
        if constexpr (EPI == 1) v = fmaxf(v, 0.f);
        size_t idx = (size_t)row * ldc + col;
        if constexpr (EPI == 2) {
          ((float*)Cout)[idx] = v + resid[idx];
        } else {
          ((unsigned short*)Cout)[idx] = f2bf(v);
        }
      }
    }
  }
}

// ---------------------------------------------------------------------------
// FFN1 with fused LN2 prologue. BM=64, BN=256 (NY=2). Reads xbuf fp32, does
// row-LN (8 lanes/row), writes swizzled bf16 A-LDS (all K=256) once; K-loop
// stages only W1. relu epilogue -> bf16.
// ---------------------------------------------------------------------------
__global__ __launch_bounds__(256) void gemm_ffn1(
    const float* __restrict__ x, const unsigned short* __restrict__ W1,
    const float* __restrict__ bias, const float* __restrict__ sa,
    const float* __restrict__ sb, unsigned short* __restrict__ out) {
  __shared__ unsigned short Alds[4 * 64 * 64];  // 32 KB, 4 k-chunks of [64][64]
  __shared__ unsigned short Blds[256 * 64];     // 32 KB
  const int tid = threadIdx.x, wave = tid >> 6, lane = tid & 63;
  const int nwg = gridDim.x;
  const int swz = (blockIdx.x & 7) * (nwg >> 3) + (blockIdx.x >> 3);
  const int row0 = (swz >> 1) * 64, ncol0 = (swz & 1) * 256;
  const int fr = lane & 15, g4 = lane >> 4, ko = g4 * 8;
  const int swr = (fr & 7) << 3;
  const int l8 = lane >> 3;
  const int lkS = ((lane & 7) ^ l8) * 8;
  const int lq = tid & 7;

  // ---- LN prologue: 2 passes x 32 rows; 8 lanes per row, 32 cols per lane
#pragma unroll
  for (int p = 0; p < 2; ++p) {
    int R = p * 32 + (tid >> 3);
    const float* xr = x + (size_t)(row0 + R) * 256 + lq * 32;
    f32x4 v[8];
#pragma unroll
    for (int j = 0; j < 8; ++j) v[j] = *(const f32x4*)(xr + j * 4);
    float s = 0.f, q = 0.f;
#pragma unroll
    for (int j = 0; j < 8; ++j) {
      s += v[j][0] + v[j][1] + v[j][2] + v[j][3];
      q += v[j][0] * v[j][0] + v[j][1] * v[j][1] + v[j][2] * v[j][2] + v[j][3] * v[j][3];
    }
#pragma unroll
    for (int off = 1; off <= 4; off <<= 1) {
      s += __shfl_xor(s, off);
      q += __shfl_xor(q, off);
    }
    float mean = s * (1.f / 256.f);
    float var = fmaxf(q - 256.f * mean * mean, 0.f) * (1.f / 255.f);
    float scl = 1.f / (sqrtf(var) + 1e-6f);
#pragma unroll
    for (int u = 0; u < 4; ++u) {
      int c0 = lq * 32 + u * 8;
      f32x4 a0 = *(const f32x4*)(sa + c0), a1 = *(const f32x4*)(sa + c0 + 4);
      f32x4 b0 = *(const f32x4*)(sb + c0), b1 = *(const f32x4*)(sb + c0 + 4);
      u16x8 o;
#pragma unroll
      for (int e = 0; e < 4; ++e) {
        o[e] = f2bf(a0[e] * (v[u * 2][e] - mean) * scl + b0[e]);
        o[e + 4] = f2bf(a1[e] * (v[u * 2 + 1][e] - mean) * scl + b1[e]);
      }
      int chunk = c0 >> 6, cs = c0 & 63;
      int slot = (cs >> 3) ^ (R & 7);
      *(u16x8*)&Alds[chunk * 4096 + R * 64 + slot * 8] = o;
    }
  }

  f32x4 acc[4][4];
#pragma unroll
  for (int i = 0; i < 4; ++i)
#pragma unroll
    for (int j = 0; j < 4; ++j) acc[i][j] = (f32x4)0.f;

  for (int kt = 0; kt < 4; ++kt) {
    __syncthreads();  // orders prologue writes / prev compute before restage
#pragma unroll
    for (int j = 0; j < 8; ++j) {
      int ci = wave * 8 + j;
      const unsigned short* src = W1 + (size_t)(ncol0 + ci * 8 + l8) * 256 + kt * 64 + lkS;
      GLD16(src, &Blds[ci * 512]);
    }
    __syncthreads();
#pragma unroll
    for (int kk = 0; kk < 2; ++kk) {
      s16x8 af[4], bfr[4];
#pragma unroll
      for (int i = 0; i < 4; ++i)
        af[i] = *(const s16x8*)&Alds[kt * 4096 + (i * 16 + fr) * 64 + ((kk * 32 + ko) ^ swr)];
#pragma unroll
      for (int j = 0; j < 4; ++j)
        bfr[j] = *(const s16x8*)&Blds[(wave * 64 + j * 16 + fr) * 64 + ((kk * 32 + ko) ^ swr)];
#pragma unroll
      for (int i = 0; i < 4; ++i)
#pragma unroll
        for (int j = 0; j < 4; ++j)
          acc[i][j] =
              __builtin_amdgcn_mfma_f32_16x16x32_bf16(af[i], bfr[j], acc[i][j], 0, 0, 0);
    }
  }

#pragma unroll
  for (int j = 0; j < 4; ++j) {
    int col = ncol0 + wave * 64 + j * 16 + fr;
    float bv = bias[col];
#pragma unroll
    for (int i = 0; i < 4; ++i)
#pragma unroll
      for (int r = 0; r < 4; ++r) {
        int row = row0 + i * 16 + g4 * 4 + r;
        float v = fmaxf(acc[i][j][r] + bv, 0.f);
        out[(size_t)row * 512 + col] = f2bf(v);
      }
  }
}

// ---------------------------------------------------------------------------
// Final conv with fused BatchNorm prologue. BM=64, N=51 (one 64-col panel).
// ---------------------------------------------------------------------------
__global__ __launch_bounds__(256) void gemm_conv(
    const float* __restrict__ x, const unsigned short* __restrict__ Wc,
    const float* __restrict__ cbias, const float* __restrict__ g,
    const float* __restrict__ bb, float* __restrict__ out) {
  __shared__ unsigned short Alds[4 * 64 * 64];  // 32 KB
  __shared__ unsigned short Blds[64 * 64];      // 8 KB
  const int tid = threadIdx.x, wave = tid >> 6, lane = tid & 63;
  const int nwg = gridDim.x;
  const int swz = (blockIdx.x & 7) * (nwg >> 3) + (blockIdx.x >> 3);
  const int row0 = swz * 64;
  const int fr = lane & 15, g4 = lane >> 4, ko = g4 * 8;
  const int swr = (fr & 7) << 3;
  const int l8 = lane >> 3;
  const int lkS = ((lane & 7) ^ l8) * 8;
  const int lq = tid & 7;
  const float is = 0.9999950000374997f;  // 1/sqrt(1+1e-5)

#pragma unroll
  for (int p = 0; p < 2; ++p) {
    int R = p * 32 + (tid >> 3);
    const float* xr = x + (size_t)(row0 + R) * 256 + lq * 32;
#pragma unroll
    for (int u = 0; u < 4; ++u) {
      int c0 = lq * 32 + u * 8;
      f32x4 v0 = *(const f32x4*)(xr + u * 8), v1 = *(const f32x4*)(xr + u * 8 + 4);
      f32x4 g0 = *(const f32x4*)(g + c0), g1 = *(const f32x4*)(g + c0 + 4);
      f32x4 b0 = *(const f32x4*)(bb + c0), b1 = *(const f32x4*)(bb + c0 + 4);
      u16x8 o;
#pragma unroll
      for (int e = 0; e < 4; ++e) {
        o[e] = f2bf(v0[e] * is * g0[e] + b0[e]);
        o[e + 4] = f2bf(v1[e] * is * g1[e] + b1[e]);
      }
      int chunk = c0 >> 6, cs = c0 & 63;
      int slot = (cs >> 3) ^ (R & 7);
      *(u16x8*)&Alds[chunk * 4096 + R * 64 + slot * 8] = o;
    }
  }

  f32x4 acc[4];
#pragma unroll
  for (int j = 0; j < 4; ++j) acc[j] = (f32x4)0.f;

  for (int kt = 0; kt < 4; ++kt) {
    __syncthreads();
#pragma unroll
    for (int j = 0; j < 2; ++j) {
      int ci = wave * 2 + j;
      int brow = ci * 8 + l8;
      if (brow > 50) brow = 50;
      const unsigned short* src = Wc + (size_t)brow * 256 + kt * 64 + lkS;
      GLD16(src, &Blds[ci * 512]);
    }
    __syncthreads();
#pragma unroll
    for (int kk = 0; kk < 2; ++kk) {
      s16x8 af, bfr[4];
      af = *(const s16x8*)&Alds[kt * 4096 + (wave * 16 + fr) * 64 + ((kk * 32 + ko) ^ swr)];
#pragma unroll
      for (int j = 0; j < 4; ++j)
        bfr[j] = *(const s16x8*)&Blds[(j * 16 + fr) * 64 + ((kk * 32 + ko) ^ swr)];
#pragma unroll
      for (int j = 0; j < 4; ++j)
        acc[j] = __builtin_amdgcn_mfma_f32_16x16x32_bf16(af, bfr[j], acc[j], 0, 0, 0);
    }
  }

#pragma unroll
  for (int j = 0; j < 4; ++j) {
    int col = j * 16 + fr;
    if (col < 51) {
      float bv = cbias[col];
#pragma unroll
      for (int r = 0; r < 4; ++r) {
        int row = row0 + wave * 16 + g4 * 4 + r;
        out[(size_t)row * 51 + col] = acc[j][r] + bv;
      }
    }
  }
}

// ---------------------------------------------------------------------------
// LayerNorm pass (still used for ln1 of layers 1,2)
// ---------------------------------------------------------------------------
__global__ __launch_bounds__(256) void ln_kernel(const float* __restrict__ x,
                                                 const float* __restrict__ a,
                                                 const float* __restrict__ b,
                                                 unsigned short* __restrict__ out) {
  const int wave = threadIdx.x >> 6, lane = threadIdx.x & 63;
  const size_t row = (size_t)blockIdx.x * 4 + wave;
  const float* xr = x + row * 256;
  f32x4 v = *(const f32x4*)(xr + lane * 4);
  float s = v[0] + v[1] + v[2] + v[3];
#pragma unroll
  for (int off = 32; off >= 1; off >>= 1) s += __shfl_xor(s, off);
  float mean = s * (1.f / 256.f);
  f32x4 d = v - mean;
  float sq = d[0] * d[0] + d[1] * d[1] + d[2] * d[2] + d[3] * d[3];
#pragma unroll
  for (int off = 32; off >= 1; off >>= 1) sq += __shfl_xor(sq, off);
  float var = sq * (1.f / 255.f);
  float scl = 1.f / (sqrtf(var) + 1e-6f);
  f32x4 av = *(const f32x4*)(a + lane * 4);
  f32x4 bv = *(const f32x4*)(b + lane * 4);
  u16x4 ob;
#pragma unroll
  for (int j = 0; j < 4; ++j) ob[j] = f2bf(av[j] * d[j] * scl + bv[j]);
  *(u16x4*)(out + row * 256 + lane * 4) = ob;
}

__global__ __launch_bounds__(256) void addpos_ln(const f32x4* __restrict__ x,
                                                 const f32x4* __restrict__ pos,
                                                 const float* __restrict__ a,
                                                 const float* __restrict__ b,
                                                 f32x4* __restrict__ xout,
                                                 unsigned short* __restrict__ lnout) {
  const int wave = threadIdx.x >> 6, lane = threadIdx.x & 63;
  const size_t row = (size_t)blockIdx.x * 4 + wave;
  f32x4 v = x[row * 64 + lane] + pos[(row % 81) * 64 + lane];
  xout[row * 64 + lane] = v;
  float s = v[0] + v[1] + v[2] + v[3];
#pragma unroll
  for (int off = 32; off >= 1; off >>= 1) s += __shfl_xor(s, off);
  float mean = s * (1.f / 256.f);
  f32x4 d = v - mean;
  float sq = d[0] * d[0] + d[1] * d[1] + d[2] * d[2] + d[3] * d[3];
#pragma unroll
  for (int off = 32; off >= 1; off >>= 1) sq += __shfl_xor(sq, off);
  float var = sq * (1.f / 255.f);
  float scl = 1.f / (sqrtf(var) + 1e-6f);
  f32x4 av = *(const f32x4*)(a + lane * 4);
  f32x4 bv = *(const f32x4*)(b + lane * 4);
  u16x4 ob;
#pragma unroll
  for (int j = 0; j < 4; ++j) ob[j] = f2bf(av[j] * d[j] * scl + bv[j]);
  *(u16x4*)(lnout + row * 256 + lane * 4) = ob;
}

// ---------------------------------------------------------------------------
// MFMA strided sparse attention (unchanged from r3/r6)
// ---------------------------------------------------------------------------
__global__ __launch_bounds__(256) void attn_mfma(const unsigned short* __restrict__ qkv,
                                                 unsigned short* __restrict__ o) {
  constexpr int LS = 40;
  const int wave = threadIdx.x >> 6, lane = threadIdx.x & 63;
  const int sid = blockIdx.x * 4 + wave;
  const int m = sid % 3, hh = (sid / 3) & 7, b = sid / 24;
  __shared__ unsigned short VtS[4][32 * LS];
  __shared__ unsigned short PlS[4][32 * LS];
  unsigned short* vt = VtS[wave];
  unsigned short* pl = PlS[wave];

  const unsigned short* base = qkv + (size_t)b * 81 * 768 + (size_t)m * 768 + hh * 32;
  const int fr = lane & 15;
  const int ko = (lane >> 4) * 8;
  const int g4 = lane >> 4;

  s16x8 qf[2], kf[2];
#pragma unroll
  for (int i = 0; i < 2; ++i) {
    int g = fr + 16 * i;
    if (g > 26) g = 26;
    const unsigned short* qp = base + (size_t)g * 2304 + ko;
    qf[i] = *(const s16x8*)qp;
    kf[i] = *(const s16x8*)(qp + 256);
  }

#pragma unroll
  for (int it = 0; it < 2; ++it) {
    int slot = it * 64 + lane;
    int g = slot >> 2, s = slot & 3;
    if (g < 27) {
      u16x8 v = *(const u16x8*)(base + (size_t)g * 2304 + 512 + s * 8);
#pragma unroll
      for (int j = 0; j < 8; ++j) vt[(s * 8 + j) * LS + g] = v[j];
    } else {
#pragma unroll
      for (int j = 0; j < 8; ++j) vt[(s * 8 + j) * LS + g] = 0;
    }
  }

  f32x4 sacc[2][2];
#pragma unroll
  for (int i = 0; i < 2; ++i)
#pragma unroll
    for (int j = 0; j < 2; ++j) sacc[i][j] = (f32x4)0.f;
#pragma unroll
  for (int i = 0; i < 2; ++i)
#pragma unroll
    for (int j = 0; j < 2; ++j)
      sacc[i][j] = __builtin_amdgcn_mfma_f32_16x16x32_bf16(qf[i], kf[j], sacc[i][j], 0, 0, 0);

  const float scale = 0.17677669529663687f;
  const bool v1 = fr < 11;
#pragma unroll
  for (int i = 0; i < 2; ++i) {
#pragma unroll
    for (int r = 0; r < 4; ++r) {
      float a0 = sacc[i][0][r] * scale;
      float a1 = v1 ? sacc[i][1][r] * scale : -3.0e38f;
      float mx = fmaxf(a0, a1);
#pragma unroll
      for (int off = 1; off <= 8; off <<= 1) mx = fmaxf(mx, __shfl_xor(mx, off));
      float e0 = __expf(a0 - mx);
      float e1 = v1 ? __expf(a1 - mx) : 0.f;
      float sm = e0 + e1;
#pragma unroll
      for (int off = 1; off <= 8; off <<= 1) sm += __shfl_xor(sm, off);
      float inv = 1.f / sm;
      int row = i * 16 + 4 * g4 + r;
      pl[row * LS + fr] = f2bf(e0 * inv);
      pl[row * LS + 16 + fr] = f2bf(e1 * inv);
    }
  }
  __syncthreads();

  s16x8 pf[2], vf[2];
#pragma unroll
  for (int i = 0; i < 2; ++i) pf[i] = *(const s16x8*)&pl[(fr + 16 * i) * LS + ko];
#pragma unroll
  for (int j = 0; j < 2; ++j) vf[j] = *(const s16x8*)&vt[(fr + 16 * j) * LS + ko];

  f32x4 oacc[2][2];
#pragma unroll
  for (int i = 0; i < 2; ++i)
#pragma unroll
    for (int j = 0; j < 2; ++j) oacc[i][j] = (f32x4)0.f;
#pragma unroll
  for (int i = 0; i < 2; ++i)
#pragma unroll
    for (int j = 0; j < 2; ++j)
      oacc[i][j] = __builtin_amdgcn_mfma_f32_16x16x32_bf16(pf[i], vf[j], oacc[i][j], 0, 0, 0);

  __syncthreads();
#pragma unroll
  for (int i = 0; i < 2; ++i)
#pragma unroll
    for (int j = 0; j < 2; ++j)
#pragma unroll
      for (int r = 0; r < 4; ++r)
        vt[(i * 16 + 4 * g4 + r) * LS + j * 16 + fr] = f2bf(oacc[i][j][r]);
  __syncthreads();

#pragma unroll
  for (int it = 0; it < 2; ++it) {
    int slot = it * 64 + lane;
    int g = slot >> 2, s = slot & 3;
    if (g < 27) {
      u16x8 v = *(const u16x8*)&vt[g * LS + s * 8];
      *(u16x8*)(o + (size_t)(b * 81 + m + 3 * g) * 256 + hh * 32 + s * 8) = v;
    }
  }
}

__global__ __launch_bounds__(256) void cvt_kernel(const f32x4* __restrict__ src,
                                                  u16x4* __restrict__ dst, int n4) {
  int i = blockIdx.x * 256 + threadIdx.x;
  if (i < n4) {
    f32x4 v = src[i];
    u16x4 o;
#pragma unroll
    for (int j = 0; j < 4; ++j) o[j] = f2bf(v[j]);
    dst[i] = o;
  }
}

__global__ __launch_bounds__(256) void qkvpack_kernel(const float* __restrict__ Wq,
                                                      const float* __restrict__ Wk,
                                                      const float* __restrict__ Wv,
                                                      u16x4* __restrict__ dst) {
  int i4 = blockIdx.x * 256 + threadIdx.x;
  int e = i4 * 4;
  int l = e / 196608;
  int r = (e / 256) % 768;
  int c = e & 255;
  const float* src;
  if (r < 256) src = Wq + (size_t)l * 65536 + r * 256 + c;
  else if (r < 512) src = Wk + (size_t)l * 65536 + (r - 256) * 256 + c;
  else src = Wv + (size_t)l * 65536 + (r - 512) * 256 + c;
  f32x4 v = *(const f32x4*)src;
  u16x4 o;
#pragma unroll
  for (int j = 0; j < 4; ++j) o[j] = f2bf(v[j]);
  dst[i4] = o;
}

__global__ __launch_bounds__(256) void biaspack_kernel(const float* __restrict__ bq,
                                                       const float* __restrict__ bk,
                                                       const float* __restrict__ bv,
                                                       float* __restrict__ dst) {
  int i = blockIdx.x * 256 + threadIdx.x;
  if (i >= 2304) return;
  int l = i / 768, r = i % 768;
  float v = (r < 256) ? bq[l * 256 + r] : (r < 512) ? bk[l * 256 + r - 256]
                                                    : bv[l * 256 + r - 512];
  dst[i] = v;
}

extern "C" void kernel_launch(void* const* d_in, const int* in_sizes, int n_in,
                              void* d_out, int out_size, void* d_ws, size_t ws_size,
                              hipStream_t stream) {
  const float* x      = (const float*)d_in[0];
  const float* pos    = (const float*)d_in[1];
  const float* ln1_a  = (const float*)d_in[2];
  const float* ln1_b  = (const float*)d_in[3];
  const float* Wq     = (const float*)d_in[4];
  const float* bq     = (const float*)d_in[5];
  const float* Wk     = (const float*)d_in[6];
  const float* bk     = (const float*)d_in[7];
  const float* Wv     = (const float*)d_in[8];
  const float* bv     = (const float*)d_in[9];
  const float* Wo     = (const float*)d_in[10];
  const float* bo     = (const float*)d_in[11];
  const float* ln2_a  = (const float*)d_in[12];
  const float* ln2_b  = (const float*)d_in[13];
  const float* W1     = (const float*)d_in[14];
  const float* b1     = (const float*)d_in[15];
  const float* W2     = (const float*)d_in[16];
  const float* b2     = (const float*)d_in[17];
  const float* bn_g   = (const float*)d_in[18];
  const float* bn_b   = (const float*)d_in[19];
  const float* conv_w = (const float*)d_in[20];
  const float* conv_b = (const float*)d_in[21];

  char* ws = (char*)d_ws;
  float* xbuf = (float*)ws;
  unsigned short* bufA = (unsigned short*)(ws + 84934656);
  unsigned short* bufB = (unsigned short*)(ws + 127401984);
  unsigned short* wqkv3 = (unsigned short*)(ws + 254803968);
  unsigned short* wo3 = wqkv3 + 589824;
  unsigned short* w13 = wo3 + 196608;
  unsigned short* w23 = w13 + 393216;
  unsigned short* cw  = w23 + 393216;
  float* qkvb3 = (float*)(ws + 254803968 + 3171840);

  auto cvt = [&](const float* s, unsigned short* d, int n) {
    int n4 = n / 4;
    cvt_kernel<<<(n4 + 255) / 256, 256, 0, stream>>>((const f32x4*)s, (u16x4*)d, n4);
  };
  qkvpack_kernel<<<576, 256, 0, stream>>>(Wq, Wk, Wv, (u16x4*)wqkv3);
  biaspack_kernel<<<9, 256, 0, stream>>>(bq, bk, bv, qkvb3);
  cvt(Wo, wo3, 196608);
  cvt(W1, w13, 393216);
  cvt(W2, w23, 393216);
  cvt(conv_w, cw, 13056);

  addpos_ln<<<20736, 256, 0, stream>>>((const f32x4*)x, (const f32x4*)pos, ln1_a, ln1_b,
                                       (f32x4*)xbuf, bufA);

  for (int l = 0; l < 3; ++l) {
    // fused QKV (8-wave tiles) -> bufB [BT,768]
    gemm8<0, 3><<<1944, 512, 0, stream>>>(bufA, wqkv3 + l * 196608, qkvb3 + l * 768,
                                          nullptr, (void*)bufB, 256, 768);
    attn_mfma<<<6144, 256, 0, stream>>>(bufB, bufA);
    // O-proj + residual -> xbuf
    gemm_bt<128, 2, 2><<<1296, 256, 0, stream>>>(bufA, wo3 + l * 65536, bo + l * 256,
                                                 xbuf, (void*)xbuf, 256, 256);
    // FFN1 with fused LN2 prologue -> bufB [BT,512]
    gemm_ffn1<<<2592, 256, 0, stream>>>(xbuf, w13 + l * 131072, b1 + l * 512,
                                        ln2_a + l * 256, ln2_b + l * 256, bufB);
    // FFN2 + residual -> xbuf
    gemm_bt<128, 2, 2><<<1296, 256, 0, stream>>>(bufB, w23 + l * 131072, b2 + l * 256,
                                                 xbuf, (void*)xbuf, 512, 256);
    if (l < 2)
      ln_kernel<<<20736, 256, 0, stream>>>(xbuf, ln1_a + (l + 1) * 256,
                                           ln1_b + (l + 1) * 256, bufA);
  }
  // final conv with fused BatchNorm prologue -> d_out fp32
  gemm_conv<<<1296, 256, 0, stream>>>(xbuf, cw, conv_b, bn_g, bn_b, (float*)d_out);
}

// Round 8
// 825.364 us; speedup vs baseline: 1.4707x; 1.0902x over previous
//
#include <hip/hip_runtime.h>

// ---------------------------------------------------------------------------
// Transformer_16784732193201 — round 8
// vs r7: drop gemm_ffn1 (latency-bound, 10% MfmaUtil); split ln restored.
// ALL large GEMMs now use the 8-wave gemm8 (BM=128,BN=256,48KB -> 3 blk/CU,
// 24 waves/CU): QKV (NY=3), FFN1 (NY=2, relu), O-proj/FFN2 (NY=1, resid).
// gemm_conv (fused BN) + addpos_ln + attn_mfma unchanged.
// ws layout:
//   xbuf  fp32 [82944,256]               @ 0
//   bufA  bf16 [82944,256]               @ 84934656
//   bufB  bf16 [82944,768]               @ 127401984
//   weights bf16 + fused bias            @ 254803968
// ---------------------------------------------------------------------------

typedef __attribute__((ext_vector_type(4))) float f32x4;
typedef __attribute__((ext_vector_type(8))) short s16x8;
typedef __attribute__((ext_vector_type(4))) unsigned short u16x4;
typedef __attribute__((ext_vector_type(8))) unsigned short u16x8;

__device__ __forceinline__ float bf2f(unsigned short u) {
  unsigned int v = ((unsigned int)u) << 16;
  return __builtin_bit_cast(float, v);
}
__device__ __forceinline__ unsigned short f2bf(float f) {
  unsigned int u = __builtin_bit_cast(unsigned int, f);
  u += 0x7fffu + ((u >> 16) & 1u);
  return (unsigned short)(u >> 16);
}

#define GLD16(gp, lp)                                                       \
  __builtin_amdgcn_global_load_lds(                                         \
      (const __attribute__((address_space(1))) void*)(gp),                  \
      (__attribute__((address_space(3))) void*)(lp), 16, 0, 0)

// ---------------------------------------------------------------------------
// 8-wave GEMM: BM=128, BN=256, 512 threads (2x4 waves), single-buffer 48KB.
// T2 XOR-swizzle (pre-swizzled source); XCD-bijective 1-D grid, y-fastest.
// EPI 0: bias -> bf16 ; 1: bias+relu -> bf16 ; 2: bias+resid -> fp32.
// ---------------------------------------------------------------------------
template <int EPI, int NY>
__global__ __launch_bounds__(512) void gemm8(
    const unsigned short* __restrict__ A, const unsigned short* __restrict__ W,
    const float* __restrict__ bias, const float* __restrict__ resid,
    void* __restrict__ Cout, int K, int ldc) {
  __shared__ unsigned short Alds[128 * 64];  // 16 KB
  __shared__ unsigned short Blds[256 * 64];  // 32 KB
  const int tid = threadIdx.x, wave = tid >> 6, lane = tid & 63;
  const int nwg = gridDim.x;
  const int swz = (blockIdx.x & 7) * (nwg >> 3) + (blockIdx.x >> 3);
  const int row0 = (swz / NY) * 128, ncol0 = (swz % NY) * 256;
  const int wr = wave >> 2, wc = wave & 3;
  const int fr = lane & 15, g4 = lane >> 4, ko = g4 * 8;
  const int swr = (fr & 7) << 3;
  const int l8 = lane >> 3;
  const int lkS = ((lane & 7) ^ l8) * 8;

  f32x4 acc[4][4];
#pragma unroll
  for (int i = 0; i < 4; ++i)
#pragma unroll
    for (int j = 0; j < 4; ++j) acc[i][j] = (f32x4)0.f;

  const int nkt = K / 64;
  for (int kt = 0; kt < nkt; ++kt) {
    __syncthreads();
#pragma unroll
    for (int j = 0; j < 2; ++j) {  // A: 16 chunks of 1KB
      int ci = wave * 2 + j;
      const unsigned short* src = A + (size_t)(row0 + ci * 8 + l8) * K + kt * 64 + lkS;
      GLD16(src, &Alds[ci * 512]);
    }
#pragma unroll
    for (int j = 0; j < 4; ++j) {  // B: 32 chunks
      int ci = wave * 4 + j;
      const unsigned short* src = W + (size_t)(ncol0 + ci * 8 + l8) * K + kt * 64 + lkS;
      GLD16(src, &Blds[ci * 512]);
    }
    __syncthreads();
#pragma unroll
    for (int kk = 0; kk < 2; ++kk) {
      s16x8 af[4], bfr[4];
#pragma unroll
      for (int i = 0; i < 4; ++i)
        af[i] = *(const s16x8*)&Alds[(wr * 64 + i * 16 + fr) * 64 + ((kk * 32 + ko) ^ swr)];
#pragma unroll
      for (int j = 0; j < 4; ++j)
        bfr[j] = *(const s16x8*)&Blds[(wc * 64 + j * 16 + fr) * 64 + ((kk * 32 + ko) ^ swr)];
#pragma unroll
      for (int i = 0; i < 4; ++i)
#pragma unroll
        for (int j = 0; j < 4; ++j)
          acc[i][j] =
              __builtin_amdgcn_mfma_f32_16x16x32_bf16(af[i], bfr[j], acc[i][j], 0, 0, 0);
    }
  }

  const int cr = g4 * 4;
#pragma unroll
  for (int i = 0; i < 4; ++i) {
#pragma unroll
    for (int j = 0; j < 4; ++j) {
      int col = ncol0 + wc * 64 + j * 16 + fr;
      float bv = bias[col];
#pragma unroll
      for (int r = 0; r < 4; ++r) {
        int row = row0 + wr * 64 + i * 16 + cr + r;
        float v = acc[i][j][r] + bv;
        if constexpr (EPI == 1) v = fmaxf(v, 0.f);
        size_t idx = (size_t)row * ldc + col;
        if constexpr (EPI == 2) {
          ((float*)Cout)[idx] = v + resid[idx];
        } else {
          ((unsigned short*)Cout)[idx] = f2bf(v);
        }
      }
    }
  }
}

// ---------------------------------------------------------------------------
// Final conv with fused BatchNorm prologue. BM=64, N=51 (one 64-col panel).
// ---------------------------------------------------------------------------
__global__ __launch_bounds__(256) void gemm_conv(
    const float* __restrict__ x, const unsigned short* __restrict__ Wc,
    const float* __restrict__ cbias, const float* __restrict__ g,
    const float* __restrict__ bb, float* __restrict__ out) {
  __shared__ unsigned short Alds[4 * 64 * 64];  // 32 KB
  __shared__ unsigned short Blds[64 * 64];      // 8 KB
  const int tid = threadIdx.x, wave = tid >> 6, lane = tid & 63;
  const int nwg = gridDim.x;
  const int swz = (blockIdx.x & 7) * (nwg >> 3) + (blockIdx.x >> 3);
  const int row0 = swz * 64;
  const int fr = lane & 15, g4 = lane >> 4, ko = g4 * 8;
  const int swr = (fr & 7) << 3;
  const int l8 = lane >> 3;
  const int lkS = ((lane & 7) ^ l8) * 8;
  const int lq = tid & 7;
  const float is = 0.9999950000374997f;  // 1/sqrt(1+1e-5)

#pragma unroll
  for (int p = 0; p < 2; ++p) {
    int R = p * 32 + (tid >> 3);
    const float* xr = x + (size_t)(row0 + R) * 256 + lq * 32;
#pragma unroll
    for (int u = 0; u < 4; ++u) {
      int c0 = lq * 32 + u * 8;
      f32x4 v0 = *(const f32x4*)(xr + u * 8), v1 = *(const f32x4*)(xr + u * 8 + 4);
      f32x4 g0 = *(const f32x4*)(g + c0), g1 = *(const f32x4*)(g + c0 + 4);
      f32x4 b0 = *(const f32x4*)(bb + c0), b1 = *(const f32x4*)(bb + c0 + 4);
      u16x8 o;
#pragma unroll
      for (int e = 0; e < 4; ++e) {
        o[e] = f2bf(v0[e] * is * g0[e] + b0[e]);
        o[e + 4] = f2bf(v1[e] * is * g1[e] + b1[e]);
      }
      int chunk = c0 >> 6, cs = c0 & 63;
      int slot = (cs >> 3) ^ (R & 7);
      *(u16x8*)&Alds[chunk * 4096 + R * 64 + slot * 8] = o;
    }
  }

  f32x4 acc[4];
#pragma unroll
  for (int j = 0; j < 4; ++j) acc[j] = (f32x4)0.f;

  for (int kt = 0; kt < 4; ++kt) {
    __syncthreads();
#pragma unroll
    for (int j = 0; j < 2; ++j) {
      int ci = wave * 2 + j;
      int brow = ci * 8 + l8;
      if (brow > 50) brow = 50;
      const unsigned short* src = Wc + (size_t)brow * 256 + kt * 64 + lkS;
      GLD16(src, &Blds[ci * 512]);
    }
    __syncthreads();
#pragma unroll
    for (int kk = 0; kk < 2; ++kk) {
      s16x8 af, bfr[4];
      af = *(const s16x8*)&Alds[kt * 4096 + (wave * 16 + fr) * 64 + ((kk * 32 + ko) ^ swr)];
#pragma unroll
      for (int j = 0; j < 4; ++j)
        bfr[j] = *(const s16x8*)&Blds[(j * 16 + fr) * 64 + ((kk * 32 + ko) ^ swr)];
#pragma unroll
      for (int j = 0; j < 4; ++j)
        acc[j] = __builtin_amdgcn_mfma_f32_16x16x32_bf16(af, bfr[j], acc[j], 0, 0, 0);
    }
  }

#pragma unroll
  for (int j = 0; j < 4; ++j) {
    int col = j * 16 + fr;
    if (col < 51) {
      float bv = cbias[col];
#pragma unroll
      for (int r = 0; r < 4; ++r) {
        int row = row0 + wave * 16 + g4 * 4 + r;
        out[(size_t)row * 51 + col] = acc[j][r] + bv;
      }
    }
  }
}

// ---------------------------------------------------------------------------
// LayerNorm: unbiased var (D-1), out = a*(x-mean)/(sqrt(var)+1e-6)+b -> bf16
// ---------------------------------------------------------------------------
__global__ __launch_bounds__(256) void ln_kernel(const float* __restrict__ x,
                                                 const float* __restrict__ a,
                                                 const float* __restrict__ b,
                                                 unsigned short* __restrict__ out) {
  const int wave = threadIdx.x >> 6, lane = threadIdx.x & 63;
  const size_t row = (size_t)blockIdx.x * 4 + wave;
  const float* xr = x + row * 256;
  f32x4 v = *(const f32x4*)(xr + lane * 4);
  float s = v[0] + v[1] + v[2] + v[3];
#pragma unroll
  for (int off = 32; off >= 1; off >>= 1) s += __shfl_xor(s, off);
  float mean = s * (1.f / 256.f);
  f32x4 d = v - mean;
  float sq = d[0] * d[0] + d[1] * d[1] + d[2] * d[2] + d[3] * d[3];
#pragma unroll
  for (int off = 32; off >= 1; off >>= 1) sq += __shfl_xor(sq, off);
  float var = sq * (1.f / 255.f);
  float scl = 1.f / (sqrtf(var) + 1e-6f);
  f32x4 av = *(const f32x4*)(a + lane * 4);
  f32x4 bv = *(const f32x4*)(b + lane * 4);
  u16x4 ob;
#pragma unroll
  for (int j = 0; j < 4; ++j) ob[j] = f2bf(av[j] * d[j] * scl + bv[j]);
  *(u16x4*)(out + row * 256 + lane * 4) = ob;
}

__global__ __launch_bounds__(256) void addpos_ln(const f32x4* __restrict__ x,
                                                 const f32x4* __restrict__ pos,
                                                 const float* __restrict__ a,
                                                 const float* __restrict__ b,
                                                 f32x4* __restrict__ xout,
                                                 unsigned short* __restrict__ lnout) {
  const int wave = threadIdx.x >> 6, lane = threadIdx.x & 63;
  const size_t row = (size_t)blockIdx.x * 4 + wave;
  f32x4 v = x[row * 64 + lane] + pos[(row % 81) * 64 + lane];
  xout[row * 64 + lane] = v;
  float s = v[0] + v[1] + v[2] + v[3];
#pragma unroll
  for (int off = 32; off >= 1; off >>= 1) s += __shfl_xor(s, off);
  float mean = s * (1.f / 256.f);
  f32x4 d = v - mean;
  float sq = d[0] * d[0] + d[1] * d[1] + d[2] * d[2] + d[3] * d[3];
#pragma unroll
  for (int off = 32; off >= 1; off >>= 1) sq += __shfl_xor(sq, off);
  float var = sq * (1.f / 255.f);
  float scl = 1.f / (sqrtf(var) + 1e-6f);
  f32x4 av = *(const f32x4*)(a + lane * 4);
  f32x4 bv = *(const f32x4*)(b + lane * 4);
  u16x4 ob;
#pragma unroll
  for (int j = 0; j < 4; ++j) ob[j] = f2bf(av[j] * d[j] * scl + bv[j]);
  *(u16x4*)(lnout + row * 256 + lane * 4) = ob;
}

// ---------------------------------------------------------------------------
// MFMA strided sparse attention. 1 wave = 1 stream (b,h,m); 4 waves/block.
// ---------------------------------------------------------------------------
__global__ __launch_bounds__(256) void attn_mfma(const unsigned short* __restrict__ qkv,
                                                 unsigned short* __restrict__ o) {
  constexpr int LS = 40;
  const int wave = threadIdx.x >> 6, lane = threadIdx.x & 63;
  const int sid = blockIdx.x * 4 + wave;
  const int m = sid % 3, hh = (sid / 3) & 7, b = sid / 24;
  __shared__ unsigned short VtS[4][32 * LS];
  __shared__ unsigned short PlS[4][32 * LS];
  unsigned short* vt = VtS[wave];
  unsigned short* pl = PlS[wave];

  const unsigned short* base = qkv + (size_t)b * 81 * 768 + (size_t)m * 768 + hh * 32;
  const int fr = lane & 15;
  const int ko = (lane >> 4) * 8;
  const int g4 = lane >> 4;

  s16x8 qf[2], kf[2];
#pragma unroll
  for (int i = 0; i < 2; ++i) {
    int g = fr + 16 * i;
    if (g > 26) g = 26;
    const unsigned short* qp = base + (size_t)g * 2304 + ko;
    qf[i] = *(const s16x8*)qp;
    kf[i] = *(const s16x8*)(qp + 256);
  }

#pragma unroll
  for (int it = 0; it < 2; ++it) {
    int slot = it * 64 + lane;
    int g = slot >> 2, s = slot & 3;
    if (g < 27) {
      u16x8 v = *(const u16x8*)(base + (size_t)g * 2304 + 512 + s * 8);
#pragma unroll
      for (int j = 0; j < 8; ++j) vt[(s * 8 + j) * LS + g] = v[j];
    } else {
#pragma unroll
      for (int j = 0; j < 8; ++j) vt[(s * 8 + j) * LS + g] = 0;
    }
  }

  f32x4 sacc[2][2];
#pragma unroll
  for (int i = 0; i < 2; ++i)
#pragma unroll
    for (int j = 0; j < 2; ++j) sacc[i][j] = (f32x4)0.f;
#pragma unroll
  for (int i = 0; i < 2; ++i)
#pragma unroll
    for (int j = 0; j < 2; ++j)
      sacc[i][j] = __builtin_amdgcn_mfma_f32_16x16x32_bf16(qf[i], kf[j], sacc[i][j], 0, 0, 0);

  const float scale = 0.17677669529663687f;
  const bool v1 = fr < 11;
#pragma unroll
  for (int i = 0; i < 2; ++i) {
#pragma unroll
    for (int r = 0; r < 4; ++r) {
      float a0 = sacc[i][0][r] * scale;
      float a1 = v1 ? sacc[i][1][r] * scale : -3.0e38f;
      float mx = fmaxf(a0, a1);
#pragma unroll
      for (int off = 1; off <= 8; off <<= 1) mx = fmaxf(mx, __shfl_xor(mx, off));
      float e0 = __expf(a0 - mx);
      float e1 = v1 ? __expf(a1 - mx) : 0.f;
      float sm = e0 + e1;
#pragma unroll
      for (int off = 1; off <= 8; off <<= 1) sm += __shfl_xor(sm, off);
      float inv = 1.f / sm;
      int row = i * 16 + 4 * g4 + r;
      pl[row * LS + fr] = f2bf(e0 * inv);
      pl[row * LS + 16 + fr] = f2bf(e1 * inv);
    }
  }
  __syncthreads();

  s16x8 pf[2], vf[2];
#pragma unroll
  for (int i = 0; i < 2; ++i) pf[i] = *(const s16x8*)&pl[(fr + 16 * i) * LS + ko];
#pragma unroll
  for (int j = 0; j < 2; ++j) vf[j] = *(const s16x8*)&vt[(fr + 16 * j) * LS + ko];

  f32x4 oacc[2][2];
#pragma unroll
  for (int i = 0; i < 2; ++i)
#pragma unroll
    for (int j = 0; j < 2; ++j) oacc[i][j] = (f32x4)0.f;
#pragma unroll
  for (int i = 0; i < 2; ++i)
#pragma unroll
    for (int j = 0; j < 2; ++j)
      oacc[i][j] = __builtin_amdgcn_mfma_f32_16x16x32_bf16(pf[i], vf[j], oacc[i][j], 0, 0, 0);

  __syncthreads();
#pragma unroll
  for (int i = 0; i < 2; ++i)
#pragma unroll
    for (int j = 0; j < 2; ++j)
#pragma unroll
      for (int r = 0; r < 4; ++r)
        vt[(i * 16 + 4 * g4 + r) * LS + j * 16 + fr] = f2bf(oacc[i][j][r]);
  __syncthreads();

#pragma unroll
  for (int it = 0; it < 2; ++it) {
    int slot = it * 64 + lane;
    int g = slot >> 2, s = slot & 3;
    if (g < 27) {
      u16x8 v = *(const u16x8*)&vt[g * LS + s * 8];
      *(u16x8*)(o + (size_t)(b * 81 + m + 3 * g) * 256 + hh * 32 + s * 8) = v;
    }
  }
}

__global__ __launch_bounds__(256) void cvt_kernel(const f32x4* __restrict__ src,
                                                  u16x4* __restrict__ dst, int n4) {
  int i = blockIdx.x * 256 + threadIdx.x;
  if (i < n4) {
    f32x4 v = src[i];
    u16x4 o;
#pragma unroll
    for (int j = 0; j < 4; ++j) o[j] = f2bf(v[j]);
    dst[i] = o;
  }
}

__global__ __launch_bounds__(256) void qkvpack_kernel(const float* __restrict__ Wq,
                                                      const float* __restrict__ Wk,
                                                      const float* __restrict__ Wv,
                                                      u16x4* __restrict__ dst) {
  int i4 = blockIdx.x * 256 + threadIdx.x;
  int e = i4 * 4;
  int l = e / 196608;
  int r = (e / 256) % 768;
  int c = e & 255;
  const float* src;
  if (r < 256) src = Wq + (size_t)l * 65536 + r * 256 + c;
  else if (r < 512) src = Wk + (size_t)l * 65536 + (r - 256) * 256 + c;
  else src = Wv + (size_t)l * 65536 + (r - 512) * 256 + c;
  f32x4 v = *(const f32x4*)src;
  u16x4 o;
#pragma unroll
  for (int j = 0; j < 4; ++j) o[j] = f2bf(v[j]);
  dst[i4] = o;
}

__global__ __launch_bounds__(256) void biaspack_kernel(const float* __restrict__ bq,
                                                       const float* __restrict__ bk,
                                                       const float* __restrict__ bv,
                                                       float* __restrict__ dst) {
  int i = blockIdx.x * 256 + threadIdx.x;
  if (i >= 2304) return;
  int l = i / 768, r = i % 768;
  float v = (r < 256) ? bq[l * 256 + r] : (r < 512) ? bk[l * 256 + r - 256]
                                                    : bv[l * 256 + r - 512];
  dst[i] = v;
}

extern "C" void kernel_launch(void* const* d_in, const int* in_sizes, int n_in,
                              void* d_out, int out_size, void* d_ws, size_t ws_size,
                              hipStream_t stream) {
  const float* x      = (const float*)d_in[0];
  const float* pos    = (const float*)d_in[1];
  const float* ln1_a  = (const float*)d_in[2];
  const float* ln1_b  = (const float*)d_in[3];
  const float* Wq     = (const float*)d_in[4];
  const float* bq     = (const float*)d_in[5];
  const float* Wk     = (const float*)d_in[6];
  const float* bk     = (const float*)d_in[7];
  const float* Wv     = (const float*)d_in[8];
  const float* bv     = (const float*)d_in[9];
  const float* Wo     = (const float*)d_in[10];
  const float* bo     = (const float*)d_in[11];
  const float* ln2_a  = (const float*)d_in[12];
  const float* ln2_b  = (const float*)d_in[13];
  const float* W1     = (const float*)d_in[14];
  const float* b1     = (const float*)d_in[15];
  const float* W2     = (const float*)d_in[16];
  const float* b2     = (const float*)d_in[17];
  const float* bn_g   = (const float*)d_in[18];
  const float* bn_b   = (const float*)d_in[19];
  const float* conv_w = (const float*)d_in[20];
  const float* conv_b = (const float*)d_in[21];

  char* ws = (char*)d_ws;
  float* xbuf = (float*)ws;
  unsigned short* bufA = (unsigned short*)(ws + 84934656);
  unsigned short* bufB = (unsigned short*)(ws + 127401984);
  unsigned short* wqkv3 = (unsigned short*)(ws + 254803968);
  unsigned short* wo3 = wqkv3 + 589824;
  unsigned short* w13 = wo3 + 196608;
  unsigned short* w23 = w13 + 393216;
  unsigned short* cw  = w23 + 393216;
  float* qkvb3 = (float*)(ws + 254803968 + 3171840);

  auto cvt = [&](const float* s, unsigned short* d, int n) {
    int n4 = n / 4;
    cvt_kernel<<<(n4 + 255) / 256, 256, 0, stream>>>((const f32x4*)s, (u16x4*)d, n4);
  };
  qkvpack_kernel<<<576, 256, 0, stream>>>(Wq, Wk, Wv, (u16x4*)wqkv3);
  biaspack_kernel<<<9, 256, 0, stream>>>(bq, bk, bv, qkvb3);
  cvt(Wo, wo3, 196608);
  cvt(W1, w13, 393216);
  cvt(W2, w23, 393216);
  cvt(conv_w, cw, 13056);

  addpos_ln<<<20736, 256, 0, stream>>>((const f32x4*)x, (const f32x4*)pos, ln1_a, ln1_b,
                                       (f32x4*)xbuf, bufA);

  for (int l = 0; l < 3; ++l) {
    // fused QKV -> bufB [BT,768]
    gemm8<0, 3><<<1944, 512, 0, stream>>>(bufA, wqkv3 + l * 196608, qkvb3 + l * 768,
                                          nullptr, (void*)bufB, 256, 768);
    attn_mfma<<<6144, 256, 0, stream>>>(bufB, bufA);
    // O-proj + residual -> xbuf
    gemm8<2, 1><<<648, 512, 0, stream>>>(bufA, wo3 + l * 65536, bo + l * 256, xbuf,
                                         (void*)xbuf, 256, 256);
    ln_kernel<<<20736, 256, 0, stream>>>(xbuf, ln2_a + l * 256, ln2_b + l * 256, bufA);
    // FFN1 (relu) -> bufB [BT,512]
    gemm8<1, 2><<<1296, 512, 0, stream>>>(bufA, w13 + l * 131072, b1 + l * 512, nullptr,
                                          (void*)bufB, 256, 512);
    // FFN2 + residual -> xbuf
    gemm8<2, 1><<<648, 512, 0, stream>>>(bufB, w23 + l * 131072, b2 + l * 256, xbuf,
                                         (void*)xbuf, 512, 256);
    if (l < 2)
      ln_kernel<<<20736, 256, 0, stream>>>(xbuf, ln1_a + (l + 1) * 256,
                                           ln1_b + (l + 1) * 256, bufA);
  }
  // final conv with fused BatchNorm prologue -> d_out fp32
  gemm_conv<<<1296, 256, 0, stream>>>(xbuf, cw, conv_b, bn_g, bn_b, (float*)d_out);
}

// Round 9
// 801.339 us; speedup vs baseline: 1.5148x; 1.0300x over previous
//
#include <hip/hip_runtime.h>

// ---------------------------------------------------------------------------
// Transformer_16784732193201 — round 9
// vs r8: LN fused into the full-row (NY=1) gemm8 epilogue (gemm8ln) — the
// shape where r4's fusion failed is gone: 512 thr, 52KB LDS, 3 blk/CU.
// O-proj+ln2 and FFN2+ln1(l+1) are each one dispatch; last FFN2 fuses BN;
// conv reads bf16 bufA directly. All 5 ln_kernel passes removed.
// ws layout:
//   xbuf  fp32 [82944,256]               @ 0
//   bufA  bf16 [82944,256]               @ 84934656
//   bufB  bf16 [82944,768]               @ 127401984
//   weights bf16 + fused bias            @ 254803968
// ---------------------------------------------------------------------------

typedef __attribute__((ext_vector_type(4))) float f32x4;
typedef __attribute__((ext_vector_type(8))) short s16x8;
typedef __attribute__((ext_vector_type(4))) unsigned short u16x4;
typedef __attribute__((ext_vector_type(8))) unsigned short u16x8;

__device__ __forceinline__ float bf2f(unsigned short u) {
  unsigned int v = ((unsigned int)u) << 16;
  return __builtin_bit_cast(float, v);
}
__device__ __forceinline__ unsigned short f2bf(float f) {
  unsigned int u = __builtin_bit_cast(unsigned int, f);
  u += 0x7fffu + ((u >> 16) & 1u);
  return (unsigned short)(u >> 16);
}

#define GLD16(gp, lp)                                                       \
  __builtin_amdgcn_global_load_lds(                                         \
      (const __attribute__((address_space(1))) void*)(gp),                  \
      (__attribute__((address_space(3))) void*)(lp), 16, 0, 0)

// ---------------------------------------------------------------------------
// 8-wave GEMM: BM=128, BN=256, 512 threads (2x4 waves), single-buffer 48KB.
// EPI 0: bias -> bf16 ; 1: bias+relu -> bf16.
// ---------------------------------------------------------------------------
template <int EPI, int NY>
__global__ __launch_bounds__(512) void gemm8(
    const unsigned short* __restrict__ A, const unsigned short* __restrict__ W,
    const float* __restrict__ bias, void* __restrict__ Cout, int K, int ldc) {
  __shared__ unsigned short Alds[128 * 64];
  __shared__ unsigned short Blds[256 * 64];
  const int tid = threadIdx.x, wave = tid >> 6, lane = tid & 63;
  const int nwg = gridDim.x;
  const int swz = (blockIdx.x & 7) * (nwg >> 3) + (blockIdx.x >> 3);
  const int row0 = (swz / NY) * 128, ncol0 = (swz % NY) * 256;
  const int wr = wave >> 2, wc = wave & 3;
  const int fr = lane & 15, g4 = lane >> 4, ko = g4 * 8;
  const int swr = (fr & 7) << 3;
  const int l8 = lane >> 3;
  const int lkS = ((lane & 7) ^ l8) * 8;

  f32x4 acc[4][4];
#pragma unroll
  for (int i = 0; i < 4; ++i)
#pragma unroll
    for (int j = 0; j < 4; ++j) acc[i][j] = (f32x4)0.f;

  const int nkt = K / 64;
  for (int kt = 0; kt < nkt; ++kt) {
    __syncthreads();
#pragma unroll
    for (int j = 0; j < 2; ++j) {
      int ci = wave * 2 + j;
      const unsigned short* src = A + (size_t)(row0 + ci * 8 + l8) * K + kt * 64 + lkS;
      GLD16(src, &Alds[ci * 512]);
    }
#pragma unroll
    for (int j = 0; j < 4; ++j) {
      int ci = wave * 4 + j;
      const unsigned short* src = W + (size_t)(ncol0 + ci * 8 + l8) * K + kt * 64 + lkS;
      GLD16(src, &Blds[ci * 512]);
    }
    __syncthreads();
#pragma unroll
    for (int kk = 0; kk < 2; ++kk) {
      s16x8 af[4], bfr[4];
#pragma unroll
      for (int i = 0; i < 4; ++i)
        af[i] = *(const s16x8*)&Alds[(wr * 64 + i * 16 + fr) * 64 + ((kk * 32 + ko) ^ swr)];
#pragma unroll
      for (int j = 0; j < 4; ++j)
        bfr[j] = *(const s16x8*)&Blds[(wc * 64 + j * 16 + fr) * 64 + ((kk * 32 + ko) ^ swr)];
#pragma unroll
      for (int i = 0; i < 4; ++i)
#pragma unroll
        for (int j = 0; j < 4; ++j)
          acc[i][j] =
              __builtin_amdgcn_mfma_f32_16x16x32_bf16(af[i], bfr[j], acc[i][j], 0, 0, 0);
    }
  }

  const int cr = g4 * 4;
#pragma unroll
  for (int i = 0; i < 4; ++i) {
#pragma unroll
    for (int j = 0; j < 4; ++j) {
      int col = ncol0 + wc * 64 + j * 16 + fr;
      float bv = bias[col];
#pragma unroll
      for (int r = 0; r < 4; ++r) {
        int row = row0 + wr * 64 + i * 16 + cr + r;
        float v = acc[i][j][r] + bv;
        if constexpr (EPI == 1) v = fmaxf(v, 0.f);
        ((unsigned short*)Cout)[(size_t)row * ldc + col] = f2bf(v);
      }
    }
  }
}

// ---------------------------------------------------------------------------
// Full-row GEMM + residual + fused norm epilogue. BM=128, BN=256=N, NY=1.
// v = acc + bias + xbuf[row,col];
// MODE 0 (LayerNorm): xout=v (fp32), lnout = sa*(v-mean)/(sqrt(var)+eps)+sb
// MODE 1 (BatchNorm): lnout = v*is*sa+sb only (xout skipped, dead).
// In-place A==lnout safe: NY=1 -> block reads only its own 128 A rows.
// ---------------------------------------------------------------------------
template <int MODE>
__global__ __launch_bounds__(512) void gemm8ln(
    const unsigned short* __restrict__ A, const unsigned short* __restrict__ W,
    const float* __restrict__ bias, float* __restrict__ xbuf,
    const float* __restrict__ sa, const float* __restrict__ sb,
    unsigned short* __restrict__ lnout, int K) {
  __shared__ unsigned short Alds[128 * 64];
  __shared__ unsigned short Blds[256 * 64];
  __shared__ float redS[128][4];
  __shared__ float redQ[128][4];
  const int tid = threadIdx.x, wave = tid >> 6, lane = tid & 63;
  const int nwg = gridDim.x;
  const int swz = (blockIdx.x & 7) * (nwg >> 3) + (blockIdx.x >> 3);
  const int row0 = swz * 128;
  const int wr = wave >> 2, wc = wave & 3;
  const int fr = lane & 15, g4 = lane >> 4, ko = g4 * 8;
  const int swr = (fr & 7) << 3;
  const int l8 = lane >> 3;
  const int lkS = ((lane & 7) ^ l8) * 8;

  f32x4 acc[4][4];
#pragma unroll
  for (int i = 0; i < 4; ++i)
#pragma unroll
    for (int j = 0; j < 4; ++j) acc[i][j] = (f32x4)0.f;

  const int nkt = K / 64;
  for (int kt = 0; kt < nkt; ++kt) {
    __syncthreads();
#pragma unroll
    for (int j = 0; j < 2; ++j) {
      int ci = wave * 2 + j;
      const unsigned short* src = A + (size_t)(row0 + ci * 8 + l8) * K + kt * 64 + lkS;
      GLD16(src, &Alds[ci * 512]);
    }
#pragma unroll
    for (int j = 0; j < 4; ++j) {
      int ci = wave * 4 + j;
      const unsigned short* src = W + (size_t)(ci * 8 + l8) * K + kt * 64 + lkS;
      GLD16(src, &Blds[ci * 512]);
    }
    __syncthreads();
#pragma unroll
    for (int kk = 0; kk < 2; ++kk) {
      s16x8 af[4], bfr[4];
#pragma unroll
      for (int i = 0; i < 4; ++i)
        af[i] = *(const s16x8*)&Alds[(wr * 64 + i * 16 + fr) * 64 + ((kk * 32 + ko) ^ swr)];
#pragma unroll
      for (int j = 0; j < 4; ++j)
        bfr[j] = *(const s16x8*)&Blds[(wc * 64 + j * 16 + fr) * 64 + ((kk * 32 + ko) ^ swr)];
#pragma unroll
      for (int i = 0; i < 4; ++i)
#pragma unroll
        for (int j = 0; j < 4; ++j)
          acc[i][j] =
              __builtin_amdgcn_mfma_f32_16x16x32_bf16(af[i], bfr[j], acc[i][j], 0, 0, 0);
    }
  }

  const int cr = g4 * 4;
  float bv[4];
#pragma unroll
  for (int j = 0; j < 4; ++j) bv[j] = bias[wc * 64 + j * 16 + fr];

  // v = acc + bias + resid; write xout (LN mode); accumulate row partials
#pragma unroll
  for (int i = 0; i < 4; ++i) {
    float s4[4] = {0.f, 0.f, 0.f, 0.f};
    float q4[4] = {0.f, 0.f, 0.f, 0.f};
#pragma unroll
    for (int j = 0; j < 4; ++j) {
      int col = wc * 64 + j * 16 + fr;
#pragma unroll
      for (int r = 0; r < 4; ++r) {
        int row = row0 + wr * 64 + i * 16 + cr + r;
        size_t idx = (size_t)row * 256 + col;
        float v = acc[i][j][r] + bv[j] + xbuf[idx];
        acc[i][j][r] = v;
        if constexpr (MODE == 0) xbuf[idx] = v;
        s4[r] += v;
        q4[r] += v * v;
      }
    }
    if constexpr (MODE == 0) {
#pragma unroll
      for (int r = 0; r < 4; ++r) {
        float s = s4[r], q = q4[r];
#pragma unroll
        for (int off = 1; off <= 8; off <<= 1) {
          s += __shfl_xor(s, off);
          q += __shfl_xor(q, off);
        }
        if (fr == 0) {
          int rl = wr * 64 + i * 16 + cr + r;
          redS[rl][wc] = s;
          redQ[rl][wc] = q;
        }
      }
    }
  }

  if constexpr (MODE == 0) {
    __syncthreads();
#pragma unroll
    for (int i = 0; i < 4; ++i) {
#pragma unroll
      for (int r = 0; r < 4; ++r) {
        int rl = wr * 64 + i * 16 + cr + r;
        float s = redS[rl][0] + redS[rl][1] + redS[rl][2] + redS[rl][3];
        float q = redQ[rl][0] + redQ[rl][1] + redQ[rl][2] + redQ[rl][3];
        float mean = s * (1.f / 256.f);
        float var = fmaxf(q - 256.f * mean * mean, 0.f) * (1.f / 255.f);
        float scl = 1.f / (sqrtf(var) + 1e-6f);
#pragma unroll
        for (int j = 0; j < 4; ++j) {
          int col = wc * 64 + j * 16 + fr;
          float o = sa[col] * (acc[i][j][r] - mean) * scl + sb[col];
          lnout[(size_t)(row0 + rl) * 256 + col] = f2bf(o);
        }
      }
    }
  } else {
    const float is = 0.9999950000374997f;  // 1/sqrt(1+1e-5)
#pragma unroll
    for (int j = 0; j < 4; ++j) {
      int col = wc * 64 + j * 16 + fr;
      float ga = sa[col] * is, bb = sb[col];
#pragma unroll
      for (int i = 0; i < 4; ++i)
#pragma unroll
        for (int r = 0; r < 4; ++r) {
          int row = row0 + wr * 64 + i * 16 + cr + r;
          lnout[(size_t)row * 256 + col] = f2bf(acc[i][j][r] * ga + bb);
        }
    }
  }
}

// ---------------------------------------------------------------------------
// Final 51-col conv: BM=128, BN=64 (clamped rows), 4 waves 2x2, bf16 in.
// ---------------------------------------------------------------------------
__global__ __launch_bounds__(256) void gemm_cv(
    const unsigned short* __restrict__ A, const unsigned short* __restrict__ W,
    const float* __restrict__ bias, float* __restrict__ out) {
  constexpr int BM = 128, BK = 64, BN = 64, WN = 32, FN = 2;
  __shared__ unsigned short Alds[BM * BK];
  __shared__ unsigned short Blds[BN * BK];
  const int tid = threadIdx.x, wave = tid >> 6, lane = tid & 63;
  const int nwg = gridDim.x;
  const int swz = (blockIdx.x & 7) * (nwg >> 3) + (blockIdx.x >> 3);
  const int row0 = swz * BM;
  const int wr = wave >> 1, wc = wave & 1;
  const int fr = lane & 15, g4 = lane >> 4, ko = g4 * 8;
  const int swr = (fr & 7) << 3;
  const int l8 = lane >> 3;
  const int lkS = ((lane & 7) ^ l8) * 8;

  f32x4 acc[4][FN];
#pragma unroll
  for (int i = 0; i < 4; ++i)
#pragma unroll
    for (int j = 0; j < FN; ++j) acc[i][j] = (f32x4)0.f;

  for (int kt = 0; kt < 4; ++kt) {
    __syncthreads();
#pragma unroll
    for (int j = 0; j < 4; ++j) {
      int ci = wave * 4 + j;
      const unsigned short* src = A + (size_t)(row0 + ci * 8 + l8) * 256 + kt * BK + lkS;
      GLD16(src, &Alds[ci * 512]);
    }
    {
      int ci = wave * 2;
      int brow = ci * 8 + l8;
      if (brow > 50) brow = 50;
      const unsigned short* src = W + (size_t)brow * 256 + kt * BK + lkS;
      GLD16(src, &Blds[ci * 512]);
      int brow2 = (ci + 1) * 8 + l8;
      if (brow2 > 50) brow2 = 50;
      const unsigned short* src2 = W + (size_t)brow2 * 256 + kt * BK + lkS;
      GLD16(src2, &Blds[(ci + 1) * 512]);
    }
    __syncthreads();
#pragma unroll
    for (int kk = 0; kk < 2; ++kk) {
      s16x8 af[4], bfr[FN];
#pragma unroll
      for (int i = 0; i < 4; ++i)
        af[i] = *(const s16x8*)&Alds[(wr * 64 + i * 16 + fr) * BK + ((kk * 32 + ko) ^ swr)];
#pragma unroll
      for (int j = 0; j < FN; ++j)
        bfr[j] = *(const s16x8*)&Blds[(wc * WN + j * 16 + fr) * BK + ((kk * 32 + ko) ^ swr)];
#pragma unroll
      for (int i = 0; i < 4; ++i)
#pragma unroll
        for (int j = 0; j < FN; ++j)
          acc[i][j] =
              __builtin_amdgcn_mfma_f32_16x16x32_bf16(af[i], bfr[j], acc[i][j], 0, 0, 0);
    }
  }

  const int cr = g4 * 4;
#pragma unroll
  for (int i = 0; i < 4; ++i) {
#pragma unroll
    for (int j = 0; j < FN; ++j) {
      int col = wc * WN + j * 16 + fr;
      if (col >= 51) continue;
      float bv = bias[col];
#pragma unroll
      for (int r = 0; r < 4; ++r) {
        int row = row0 + wr * 64 + i * 16 + cr + r;
        out[(size_t)row * 51 + col] = acc[i][j][r] + bv;
      }
    }
  }
}

// ---------------------------------------------------------------------------
// Fused x+pos -> xbuf (fp32) and LayerNorm -> bufA (bf16). 1 wave per row.
// ---------------------------------------------------------------------------
__global__ __launch_bounds__(256) void addpos_ln(const f32x4* __restrict__ x,
                                                 const f32x4* __restrict__ pos,
                                                 const float* __restrict__ a,
                                                 const float* __restrict__ b,
                                                 f32x4* __restrict__ xout,
                                                 unsigned short* __restrict__ lnout) {
  const int wave = threadIdx.x >> 6, lane = threadIdx.x & 63;
  const size_t row = (size_t)blockIdx.x * 4 + wave;
  f32x4 v = x[row * 64 + lane] + pos[(row % 81) * 64 + lane];
  xout[row * 64 + lane] = v;
  float s = v[0] + v[1] + v[2] + v[3];
#pragma unroll
  for (int off = 32; off >= 1; off >>= 1) s += __shfl_xor(s, off);
  float mean = s * (1.f / 256.f);
  f32x4 d = v - mean;
  float sq = d[0] * d[0] + d[1] * d[1] + d[2] * d[2] + d[3] * d[3];
#pragma unroll
  for (int off = 32; off >= 1; off >>= 1) sq += __shfl_xor(sq, off);
  float var = sq * (1.f / 255.f);
  float scl = 1.f / (sqrtf(var) + 1e-6f);
  f32x4 av = *(const f32x4*)(a + lane * 4);
  f32x4 bv = *(const f32x4*)(b + lane * 4);
  u16x4 ob;
#pragma unroll
  for (int j = 0; j < 4; ++j) ob[j] = f2bf(av[j] * d[j] * scl + bv[j]);
  *(u16x4*)(lnout + row * 256 + lane * 4) = ob;
}

// ---------------------------------------------------------------------------
// MFMA strided sparse attention. 1 wave = 1 stream (b,h,m); 4 waves/block.
// ---------------------------------------------------------------------------
__global__ __launch_bounds__(256) void attn_mfma(const unsigned short* __restrict__ qkv,
                                                 unsigned short* __restrict__ o) {
  constexpr int LS = 40;
  const int wave = threadIdx.x >> 6, lane = threadIdx.x & 63;
  const int sid = blockIdx.x * 4 + wave;
  const int m = sid % 3, hh = (sid / 3) & 7, b = sid / 24;
  __shared__ unsigned short VtS[4][32 * LS];
  __shared__ unsigned short PlS[4][32 * LS];
  unsigned short* vt = VtS[wave];
  unsigned short* pl = PlS[wave];

  const unsigned short* base = qkv + (size_t)b * 81 * 768 + (size_t)m * 768 + hh * 32;
  const int fr = lane & 15;
  const int ko = (lane >> 4) * 8;
  const int g4 = lane >> 4;

  s16x8 qf[2], kf[2];
#pragma unroll
  for (int i = 0; i < 2; ++i) {
    int g = fr + 16 * i;
    if (g > 26) g = 26;
    const unsigned short* qp = base + (size_t)g * 2304 + ko;
    qf[i] = *(const s16x8*)qp;
    kf[i] = *(const s16x8*)(qp + 256);
  }

#pragma unroll
  for (int it = 0; it < 2; ++it) {
    int slot = it * 64 + lane;
    int g = slot >> 2, s = slot & 3;
    if (g < 27) {
      u16x8 v = *(const u16x8*)(base + (size_t)g * 2304 + 512 + s * 8);
#pragma unroll
      for (int j = 0; j < 8; ++j) vt[(s * 8 + j) * LS + g] = v[j];
    } else {
#pragma unroll
      for (int j = 0; j < 8; ++j) vt[(s * 8 + j) * LS + g] = 0;
    }
  }

  f32x4 sacc[2][2];
#pragma unroll
  for (int i = 0; i < 2; ++i)
#pragma unroll
    for (int j = 0; j < 2; ++j) sacc[i][j] = (f32x4)0.f;
#pragma unroll
  for (int i = 0; i < 2; ++i)
#pragma unroll
    for (int j = 0; j < 2; ++j)
      sacc[i][j] = __builtin_amdgcn_mfma_f32_16x16x32_bf16(qf[i], kf[j], sacc[i][j], 0, 0, 0);

  const float scale = 0.17677669529663687f;
  const bool v1 = fr < 11;
#pragma unroll
  for (int i = 0; i < 2; ++i) {
#pragma unroll
    for (int r = 0; r < 4; ++r) {
      float a0 = sacc[i][0][r] * scale;
      float a1 = v1 ? sacc[i][1][r] * scale : -3.0e38f;
      float mx = fmaxf(a0, a1);
#pragma unroll
      for (int off = 1; off <= 8; off <<= 1) mx = fmaxf(mx, __shfl_xor(mx, off));
      float e0 = __expf(a0 - mx);
      float e1 = v1 ? __expf(a1 - mx) : 0.f;
      float sm = e0 + e1;
#pragma unroll
      for (int off = 1; off <= 8; off <<= 1) sm += __shfl_xor(sm, off);
      float inv = 1.f / sm;
      int row = i * 16 + 4 * g4 + r;
      pl[row * LS + fr] = f2bf(e0 * inv);
      pl[row * LS + 16 + fr] = f2bf(e1 * inv);
    }
  }
  __syncthreads();

  s16x8 pf[2], vf[2];
#pragma unroll
  for (int i = 0; i < 2; ++i) pf[i] = *(const s16x8*)&pl[(fr + 16 * i) * LS + ko];
#pragma unroll
  for (int j = 0; j < 2; ++j) vf[j] = *(const s16x8*)&vt[(fr + 16 * j) * LS + ko];

  f32x4 oacc[2][2];
#pragma unroll
  for (int i = 0; i < 2; ++i)
#pragma unroll
    for (int j = 0; j < 2; ++j) oacc[i][j] = (f32x4)0.f;
#pragma unroll
  for (int i = 0; i < 2; ++i)
#pragma unroll
    for (int j = 0; j < 2; ++j)
      oacc[i][j] = __builtin_amdgcn_mfma_f32_16x16x32_bf16(pf[i], vf[j], oacc[i][j], 0, 0, 0);

  __syncthreads();
#pragma unroll
  for (int i = 0; i < 2; ++i)
#pragma unroll
    for (int j = 0; j < 2; ++j)
#pragma unroll
      for (int r = 0; r < 4; ++r)
        vt[(i * 16 + 4 * g4 + r) * LS + j * 16 + fr] = f2bf(oacc[i][j][r]);
  __syncthreads();

#pragma unroll
  for (int it = 0; it < 2; ++it) {
    int slot = it * 64 + lane;
    int g = slot >> 2, s = slot & 3;
    if (g < 27) {
      u16x8 v = *(const u16x8*)&vt[g * LS + s * 8];
      *(u16x8*)(o + (size_t)(b * 81 + m + 3 * g) * 256 + hh * 32 + s * 8) = v;
    }
  }
}

__global__ __launch_bounds__(256) void cvt_kernel(const f32x4* __restrict__ src,
                                                  u16x4* __restrict__ dst, int n4) {
  int i = blockIdx.x * 256 + threadIdx.x;
  if (i < n4) {
    f32x4 v = src[i];
    u16x4 o;
#pragma unroll
    for (int j = 0; j < 4; ++j) o[j] = f2bf(v[j]);
    dst[i] = o;
  }
}

__global__ __launch_bounds__(256) void qkvpack_kernel(const float* __restrict__ Wq,
                                                      const float* __restrict__ Wk,
                                                      const float* __restrict__ Wv,
                                                      u16x4* __restrict__ dst) {
  int i4 = blockIdx.x * 256 + threadIdx.x;
  int e = i4 * 4;
  int l = e / 196608;
  int r = (e / 256) % 768;
  int c = e & 255;
  const float* src;
  if (r < 256) src = Wq + (size_t)l * 65536 + r * 256 + c;
  else if (r < 512) src = Wk + (size_t)l * 65536 + (r - 256) * 256 + c;
  else src = Wv + (size_t)l * 65536 + (r - 512) * 256 + c;
  f32x4 v = *(const f32x4*)src;
  u16x4 o;
#pragma unroll
  for (int j = 0; j < 4; ++j) o[j] = f2bf(v[j]);
  dst[i4] = o;
}

__global__ __launch_bounds__(256) void biaspack_kernel(const float* __restrict__ bq,
                                                       const float* __restrict__ bk,
                                                       const float* __restrict__ bv,
                                                       float* __restrict__ dst) {
  int i = blockIdx.x * 256 + threadIdx.x;
  if (i >= 2304) return;
  int l = i / 768, r = i % 768;
  float v = (r < 256) ? bq[l * 256 + r] : (r < 512) ? bk[l * 256 + r - 256]
                                                    : bv[l * 256 + r - 512];
  dst[i] = v;
}

extern "C" void kernel_launch(void* const* d_in, const int* in_sizes, int n_in,
                              void* d_out, int out_size, void* d_ws, size_t ws_size,
                              hipStream_t stream) {
  const float* x      = (const float*)d_in[0];
  const float* pos    = (const float*)d_in[1];
  const float* ln1_a  = (const float*)d_in[2];
  const float* ln1_b  = (const float*)d_in[3];
  const float* Wq     = (const float*)d_in[4];
  const float* bq     = (const float*)d_in[5];
  const float* Wk     = (const float*)d_in[6];
  const float* bk     = (const float*)d_in[7];
  const float* Wv     = (const float*)d_in[8];
  const float* bv     = (const float*)d_in[9];
  const float* Wo     = (const float*)d_in[10];
  const float* bo     = (const float*)d_in[11];
  const float* ln2_a  = (const float*)d_in[12];
  const float* ln2_b  = (const float*)d_in[13];
  const float* W1     = (const float*)d_in[14];
  const float* b1     = (const float*)d_in[15];
  const float* W2     = (const float*)d_in[16];
  const float* b2     = (const float*)d_in[17];
  const float* bn_g   = (const float*)d_in[18];
  const float* bn_b   = (const float*)d_in[19];
  const float* conv_w = (const float*)d_in[20];
  const float* conv_b = (const float*)d_in[21];

  char* ws = (char*)d_ws;
  float* xbuf = (float*)ws;
  unsigned short* bufA = (unsigned short*)(ws + 84934656);
  unsigned short* bufB = (unsigned short*)(ws + 127401984);
  unsigned short* wqkv3 = (unsigned short*)(ws + 254803968);
  unsigned short* wo3 = wqkv3 + 589824;
  unsigned short* w13 = wo3 + 196608;
  unsigned short* w23 = w13 + 393216;
  unsigned short* cw  = w23 + 393216;
  float* qkvb3 = (float*)(ws + 254803968 + 3171840);

  auto cvt = [&](const float* s, unsigned short* d, int n) {
    int n4 = n / 4;
    cvt_kernel<<<(n4 + 255) / 256, 256, 0, stream>>>((const f32x4*)s, (u16x4*)d, n4);
  };
  qkvpack_kernel<<<576, 256, 0, stream>>>(Wq, Wk, Wv, (u16x4*)wqkv3);
  biaspack_kernel<<<9, 256, 0, stream>>>(bq, bk, bv, qkvb3);
  cvt(Wo, wo3, 196608);
  cvt(W1, w13, 393216);
  cvt(W2, w23, 393216);
  cvt(conv_w, cw, 13056);

  addpos_ln<<<20736, 256, 0, stream>>>((const f32x4*)x, (const f32x4*)pos, ln1_a, ln1_b,
                                       (f32x4*)xbuf, bufA);

  for (int l = 0; l < 3; ++l) {
    // fused QKV -> bufB [BT,768]
    gemm8<0, 3><<<1944, 512, 0, stream>>>(bufA, wqkv3 + l * 196608, qkvb3 + l * 768,
                                          (void*)bufB, 256, 768);
    attn_mfma<<<6144, 256, 0, stream>>>(bufB, bufA);
    // O-proj + resid -> xbuf ; LN2 -> bufA (one dispatch)
    gemm8ln<0><<<648, 512, 0, stream>>>(bufA, wo3 + l * 65536, bo + l * 256, xbuf,
                                        ln2_a + l * 256, ln2_b + l * 256, bufA, 256);
    // FFN1 (relu) -> bufB [BT,512]
    gemm8<1, 2><<<1296, 512, 0, stream>>>(bufA, w13 + l * 131072, b1 + l * 512,
                                          (void*)bufB, 256, 512);
    if (l < 2) {
      // FFN2 + resid -> xbuf ; LN1(l+1) -> bufA
      gemm8ln<0><<<648, 512, 0, stream>>>(bufB, w23 + l * 131072, b2 + l * 256, xbuf,
                                          ln1_a + (l + 1) * 256, ln1_b + (l + 1) * 256,
                                          bufA, 512);
    } else {
      // FFN2 + resid ; BatchNorm -> bufA (xbuf dead afterwards)
      gemm8ln<1><<<648, 512, 0, stream>>>(bufB, w23 + l * 131072, b2 + l * 256, xbuf,
                                          bn_g, bn_b, bufA, 512);
    }
  }
  // final conv reads bf16 bufA -> d_out fp32
  gemm_cv<<<648, 256, 0, stream>>>(bufA, cw, conv_b, (float*)d_out);
}

// Round 10
// 767.430 us; speedup vs baseline: 1.5817x; 1.0442x over previous
//
#include <hip/hip_runtime.h>

// ---------------------------------------------------------------------------
// Transformer_16784732193201 — round 10
// vs r9: residual stream stored in BF16 (xres) instead of fp32 xbuf.
// Accumulation stays fp32 in registers; only the stored stream is rounded.
// Cuts ~85 MB/dispatch from the 6 gemm8ln passes (the current bottleneck:
// MfmaUtil 5%, 30% HBM — pure traffic) and 42 MB from addpos_ln.
// ws layout:
//   xres  bf16 [82944,256]               @ 0           (42,467,328 B)
//   bufA  bf16 [82944,256]               @ 84934656
//   bufB  bf16 [82944,768]               @ 127401984
//   weights bf16 + fused bias            @ 254803968
// ---------------------------------------------------------------------------

typedef __attribute__((ext_vector_type(4))) float f32x4;
typedef __attribute__((ext_vector_type(8))) short s16x8;
typedef __attribute__((ext_vector_type(4))) unsigned short u16x4;
typedef __attribute__((ext_vector_type(8))) unsigned short u16x8;

__device__ __forceinline__ float bf2f(unsigned short u) {
  unsigned int v = ((unsigned int)u) << 16;
  return __builtin_bit_cast(float, v);
}
__device__ __forceinline__ unsigned short f2bf(float f) {
  unsigned int u = __builtin_bit_cast(unsigned int, f);
  u += 0x7fffu + ((u >> 16) & 1u);
  return (unsigned short)(u >> 16);
}

#define GLD16(gp, lp)                                                       \
  __builtin_amdgcn_global_load_lds(                                         \
      (const __attribute__((address_space(1))) void*)(gp),                  \
      (__attribute__((address_space(3))) void*)(lp), 16, 0, 0)

// ---------------------------------------------------------------------------
// 8-wave GEMM: BM=128, BN=256, 512 threads (2x4 waves), single-buffer 48KB.
// EPI 0: bias -> bf16 ; 1: bias+relu -> bf16.
// ---------------------------------------------------------------------------
template <int EPI, int NY>
__global__ __launch_bounds__(512) void gemm8(
    const unsigned short* __restrict__ A, const unsigned short* __restrict__ W,
    const float* __restrict__ bias, void* __restrict__ Cout, int K, int ldc) {
  __shared__ unsigned short Alds[128 * 64];
  __shared__ unsigned short Blds[256 * 64];
  const int tid = threadIdx.x, wave = tid >> 6, lane = tid & 63;
  const int nwg = gridDim.x;
  const int swz = (blockIdx.x & 7) * (nwg >> 3) + (blockIdx.x >> 3);
  const int row0 = (swz / NY) * 128, ncol0 = (swz % NY) * 256;
  const int wr = wave >> 2, wc = wave & 3;
  const int fr = lane & 15, g4 = lane >> 4, ko = g4 * 8;
  const int swr = (fr & 7) << 3;
  const int l8 = lane >> 3;
  const int lkS = ((lane & 7) ^ l8) * 8;

  f32x4 acc[4][4];
#pragma unroll
  for (int i = 0; i < 4; ++i)
#pragma unroll
    for (int j = 0; j < 4; ++j) acc[i][j] = (f32x4)0.f;

  const int nkt = K / 64;
  for (int kt = 0; kt < nkt; ++kt) {
    __syncthreads();
#pragma unroll
    for (int j = 0; j < 2; ++j) {
      int ci = wave * 2 + j;
      const unsigned short* src = A + (size_t)(row0 + ci * 8 + l8) * K + kt * 64 + lkS;
      GLD16(src, &Alds[ci * 512]);
    }
#pragma unroll
    for (int j = 0; j < 4; ++j) {
      int ci = wave * 4 + j;
      const unsigned short* src = W + (size_t)(ncol0 + ci * 8 + l8) * K + kt * 64 + lkS;
      GLD16(src, &Blds[ci * 512]);
    }
    __syncthreads();
#pragma unroll
    for (int kk = 0; kk < 2; ++kk) {
      s16x8 af[4], bfr[4];
#pragma unroll
      for (int i = 0; i < 4; ++i)
        af[i] = *(const s16x8*)&Alds[(wr * 64 + i * 16 + fr) * 64 + ((kk * 32 + ko) ^ swr)];
#pragma unroll
      for (int j = 0; j < 4; ++j)
        bfr[j] = *(const s16x8*)&Blds[(wc * 64 + j * 16 + fr) * 64 + ((kk * 32 + ko) ^ swr)];
#pragma unroll
      for (int i = 0; i < 4; ++i)
#pragma unroll
        for (int j = 0; j < 4; ++j)
          acc[i][j] =
              __builtin_amdgcn_mfma_f32_16x16x32_bf16(af[i], bfr[j], acc[i][j], 0, 0, 0);
    }
  }

  const int cr = g4 * 4;
#pragma unroll
  for (int i = 0; i < 4; ++i) {
#pragma unroll
    for (int j = 0; j < 4; ++j) {
      int col = ncol0 + wc * 64 + j * 16 + fr;
      float bv = bias[col];
#pragma unroll
      for (int r = 0; r < 4; ++r) {
        int row = row0 + wr * 64 + i * 16 + cr + r;
        float v = acc[i][j][r] + bv;
        if constexpr (EPI == 1) v = fmaxf(v, 0.f);
        ((unsigned short*)Cout)[(size_t)row * ldc + col] = f2bf(v);
      }
    }
  }
}

// ---------------------------------------------------------------------------
// Full-row GEMM + bf16 residual + fused norm epilogue. BM=128, BN=256, NY=1.
// v = acc + bias + bf2f(xres[row,col]);
// MODE 0 (LayerNorm): xres=f2bf(v), lnout = sa*(v-mean)/(sqrt(var)+eps)+sb
// MODE 1 (BatchNorm): lnout = v*is*sa+sb only (xres not updated, dead).
// In-place A==lnout safe: NY=1 -> block reads only its own 128 A rows.
// ---------------------------------------------------------------------------
template <int MODE>
__global__ __launch_bounds__(512) void gemm8ln(
    const unsigned short* __restrict__ A, const unsigned short* __restrict__ W,
    const float* __restrict__ bias, unsigned short* __restrict__ xres,
    const float* __restrict__ sa, const float* __restrict__ sb,
    unsigned short* __restrict__ lnout, int K) {
  __shared__ unsigned short Alds[128 * 64];
  __shared__ unsigned short Blds[256 * 64];
  __shared__ float redS[128][4];
  __shared__ float redQ[128][4];
  const int tid = threadIdx.x, wave = tid >> 6, lane = tid & 63;
  const int nwg = gridDim.x;
  const int swz = (blockIdx.x & 7) * (nwg >> 3) + (blockIdx.x >> 3);
  const int row0 = swz * 128;
  const int wr = wave >> 2, wc = wave & 3;
  const int fr = lane & 15, g4 = lane >> 4, ko = g4 * 8;
  const int swr = (fr & 7) << 3;
  const int l8 = lane >> 3;
  const int lkS = ((lane & 7) ^ l8) * 8;

  f32x4 acc[4][4];
#pragma unroll
  for (int i = 0; i < 4; ++i)
#pragma unroll
    for (int j = 0; j < 4; ++j) acc[i][j] = (f32x4)0.f;

  const int nkt = K / 64;
  for (int kt = 0; kt < nkt; ++kt) {
    __syncthreads();
#pragma unroll
    for (int j = 0; j < 2; ++j) {
      int ci = wave * 2 + j;
      const unsigned short* src = A + (size_t)(row0 + ci * 8 + l8) * K + kt * 64 + lkS;
      GLD16(src, &Alds[ci * 512]);
    }
#pragma unroll
    for (int j = 0; j < 4; ++j) {
      int ci = wave * 4 + j;
      const unsigned short* src = W + (size_t)(ci * 8 + l8) * K + kt * 64 + lkS;
      GLD16(src, &Blds[ci * 512]);
    }
    __syncthreads();
#pragma unroll
    for (int kk = 0; kk < 2; ++kk) {
      s16x8 af[4], bfr[4];
#pragma unroll
      for (int i = 0; i < 4; ++i)
        af[i] = *(const s16x8*)&Alds[(wr * 64 + i * 16 + fr) * 64 + ((kk * 32 + ko) ^ swr)];
#pragma unroll
      for (int j = 0; j < 4; ++j)
        bfr[j] = *(const s16x8*)&Blds[(wc * 64 + j * 16 + fr) * 64 + ((kk * 32 + ko) ^ swr)];
#pragma unroll
      for (int i = 0; i < 4; ++i)
#pragma unroll
        for (int j = 0; j < 4; ++j)
          acc[i][j] =
              __builtin_amdgcn_mfma_f32_16x16x32_bf16(af[i], bfr[j], acc[i][j], 0, 0, 0);
    }
  }

  const int cr = g4 * 4;
  float bv[4];
#pragma unroll
  for (int j = 0; j < 4; ++j) bv[j] = bias[wc * 64 + j * 16 + fr];

  // v = acc + bias + resid(bf16); update xres (LN mode); row partial stats
#pragma unroll
  for (int i = 0; i < 4; ++i) {
    float s4[4] = {0.f, 0.f, 0.f, 0.f};
    float q4[4] = {0.f, 0.f, 0.f, 0.f};
#pragma unroll
    for (int j = 0; j < 4; ++j) {
      int col = wc * 64 + j * 16 + fr;
#pragma unroll
      for (int r = 0; r < 4; ++r) {
        int row = row0 + wr * 64 + i * 16 + cr + r;
        size_t idx = (size_t)row * 256 + col;
        float v = acc[i][j][r] + bv[j] + bf2f(xres[idx]);
        acc[i][j][r] = v;
        if constexpr (MODE == 0) xres[idx] = f2bf(v);
        s4[r] += v;
        q4[r] += v * v;
      }
    }
    if constexpr (MODE == 0) {
#pragma unroll
      for (int r = 0; r < 4; ++r) {
        float s = s4[r], q = q4[r];
#pragma unroll
        for (int off = 1; off <= 8; off <<= 1) {
          s += __shfl_xor(s, off);
          q += __shfl_xor(q, off);
        }
        if (fr == 0) {
          int rl = wr * 64 + i * 16 + cr + r;
          redS[rl][wc] = s;
          redQ[rl][wc] = q;
        }
      }
    }
  }

  if constexpr (MODE == 0) {
    __syncthreads();
#pragma unroll
    for (int i = 0; i < 4; ++i) {
#pragma unroll
      for (int r = 0; r < 4; ++r) {
        int rl = wr * 64 + i * 16 + cr + r;
        float s = redS[rl][0] + redS[rl][1] + redS[rl][2] + redS[rl][3];
        float q = redQ[rl][0] + redQ[rl][1] + redQ[rl][2] + redQ[rl][3];
        float mean = s * (1.f / 256.f);
        float var = fmaxf(q - 256.f * mean * mean, 0.f) * (1.f / 255.f);
        float scl = 1.f / (sqrtf(var) + 1e-6f);
#pragma unroll
        for (int j = 0; j < 4; ++j) {
          int col = wc * 64 + j * 16 + fr;
          float o = sa[col] * (acc[i][j][r] - mean) * scl + sb[col];
          lnout[(size_t)(row0 + rl) * 256 + col] = f2bf(o);
        }
      }
    }
  } else {
    const float is = 0.9999950000374997f;  // 1/sqrt(1+1e-5)
#pragma unroll
    for (int j = 0; j < 4; ++j) {
      int col = wc * 64 + j * 16 + fr;
      float ga = sa[col] * is, bb = sb[col];
#pragma unroll
      for (int i = 0; i < 4; ++i)
#pragma unroll
        for (int r = 0; r < 4; ++r) {
          int row = row0 + wr * 64 + i * 16 + cr + r;
          lnout[(size_t)row * 256 + col] = f2bf(acc[i][j][r] * ga + bb);
        }
    }
  }
}

// ---------------------------------------------------------------------------
// Final 51-col conv: BM=128, BN=64 (clamped rows), 4 waves 2x2, bf16 in.
// ---------------------------------------------------------------------------
__global__ __launch_bounds__(256) void gemm_cv(
    const unsigned short* __restrict__ A, const unsigned short* __restrict__ W,
    const float* __restrict__ bias, float* __restrict__ out) {
  constexpr int BM = 128, BK = 64, BN = 64, WN = 32, FN = 2;
  __shared__ unsigned short Alds[BM * BK];
  __shared__ unsigned short Blds[BN * BK];
  const int tid = threadIdx.x, wave = tid >> 6, lane = tid & 63;
  const int nwg = gridDim.x;
  const int swz = (blockIdx.x & 7) * (nwg >> 3) + (blockIdx.x >> 3);
  const int row0 = swz * BM;
  const int wr = wave >> 1, wc = wave & 1;
  const int fr = lane & 15, g4 = lane >> 4, ko = g4 * 8;
  const int swr = (fr & 7) << 3;
  const int l8 = lane >> 3;
  const int lkS = ((lane & 7) ^ l8) * 8;

  f32x4 acc[4][FN];
#pragma unroll
  for (int i = 0; i < 4; ++i)
#pragma unroll
    for (int j = 0; j < FN; ++j) acc[i][j] = (f32x4)0.f;

  for (int kt = 0; kt < 4; ++kt) {
    __syncthreads();
#pragma unroll
    for (int j = 0; j < 4; ++j) {
      int ci = wave * 4 + j;
      const unsigned short* src = A + (size_t)(row0 + ci * 8 + l8) * 256 + kt * BK + lkS;
      GLD16(src, &Alds[ci * 512]);
    }
    {
      int ci = wave * 2;
      int brow = ci * 8 + l8;
      if (brow > 50) brow = 50;
      const unsigned short* src = W + (size_t)brow * 256 + kt * BK + lkS;
      GLD16(src, &Blds[ci * 512]);
      int brow2 = (ci + 1) * 8 + l8;
      if (brow2 > 50) brow2 = 50;
      const unsigned short* src2 = W + (size_t)brow2 * 256 + kt * BK + lkS;
      GLD16(src2, &Blds[(ci + 1) * 512]);
    }
    __syncthreads();
#pragma unroll
    for (int kk = 0; kk < 2; ++kk) {
      s16x8 af[4], bfr[FN];
#pragma unroll
      for (int i = 0; i < 4; ++i)
        af[i] = *(const s16x8*)&Alds[(wr * 64 + i * 16 + fr) * BK + ((kk * 32 + ko) ^ swr)];
#pragma unroll
      for (int j = 0; j < FN; ++j)
        bfr[j] = *(const s16x8*)&Blds[(wc * WN + j * 16 + fr) * BK + ((kk * 32 + ko) ^ swr)];
#pragma unroll
      for (int i = 0; i < 4; ++i)
#pragma unroll
        for (int j = 0; j < FN; ++j)
          acc[i][j] =
              __builtin_amdgcn_mfma_f32_16x16x32_bf16(af[i], bfr[j], acc[i][j], 0, 0, 0);
    }
  }

  const int cr = g4 * 4;
#pragma unroll
  for (int i = 0; i < 4; ++i) {
#pragma unroll
    for (int j = 0; j < FN; ++j) {
      int col = wc * WN + j * 16 + fr;
      if (col >= 51) continue;
      float bv = bias[col];
#pragma unroll
      for (int r = 0; r < 4; ++r) {
        int row = row0 + wr * 64 + i * 16 + cr + r;
        out[(size_t)row * 51 + col] = acc[i][j][r] + bv;
      }
    }
  }
}

// ---------------------------------------------------------------------------
// Fused x+pos -> xres (bf16) and LayerNorm -> bufA (bf16). 1 wave per row.
// ---------------------------------------------------------------------------
__global__ __launch_bounds__(256) void addpos_ln(const f32x4* __restrict__ x,
                                                 const f32x4* __restrict__ pos,
                                                 const float* __restrict__ a,
                                                 const float* __restrict__ b,
                                                 unsigned short* __restrict__ xres,
                                                 unsigned short* __restrict__ lnout) {
  const int wave = threadIdx.x >> 6, lane = threadIdx.x & 63;
  const size_t row = (size_t)blockIdx.x * 4 + wave;
  f32x4 v = x[row * 64 + lane] + pos[(row % 81) * 64 + lane];
  u16x4 xb;
#pragma unroll
  for (int j = 0; j < 4; ++j) xb[j] = f2bf(v[j]);
  *(u16x4*)(xres + row * 256 + lane * 4) = xb;
  float s = v[0] + v[1] + v[2] + v[3];
#pragma unroll
  for (int off = 32; off >= 1; off >>= 1) s += __shfl_xor(s, off);
  float mean = s * (1.f / 256.f);
  f32x4 d = v - mean;
  float sq = d[0] * d[0] + d[1] * d[1] + d[2] * d[2] + d[3] * d[3];
#pragma unroll
  for (int off = 32; off >= 1; off >>= 1) sq += __shfl_xor(sq, off);
  float var = sq * (1.f / 255.f);
  float scl = 1.f / (sqrtf(var) + 1e-6f);
  f32x4 av = *(const f32x4*)(a + lane * 4);
  f32x4 bv = *(const f32x4*)(b + lane * 4);
  u16x4 ob;
#pragma unroll
  for (int j = 0; j < 4; ++j) ob[j] = f2bf(av[j] * d[j] * scl + bv[j]);
  *(u16x4*)(lnout + row * 256 + lane * 4) = ob;
}

// ---------------------------------------------------------------------------
// MFMA strided sparse attention. 1 wave = 1 stream (b,h,m); 4 waves/block.
// ---------------------------------------------------------------------------
__global__ __launch_bounds__(256) void attn_mfma(const unsigned short* __restrict__ qkv,
                                                 unsigned short* __restrict__ o) {
  constexpr int LS = 40;
  const int wave = threadIdx.x >> 6, lane = threadIdx.x & 63;
  const int sid = blockIdx.x * 4 + wave;
  const int m = sid % 3, hh = (sid / 3) & 7, b = sid / 24;
  __shared__ unsigned short VtS[4][32 * LS];
  __shared__ unsigned short PlS[4][32 * LS];
  unsigned short* vt = VtS[wave];
  unsigned short* pl = PlS[wave];

  const unsigned short* base = qkv + (size_t)b * 81 * 768 + (size_t)m * 768 + hh * 32;
  const int fr = lane & 15;
  const int ko = (lane >> 4) * 8;
  const int g4 = lane >> 4;

  s16x8 qf[2], kf[2];
#pragma unroll
  for (int i = 0; i < 2; ++i) {
    int g = fr + 16 * i;
    if (g > 26) g = 26;
    const unsigned short* qp = base + (size_t)g * 2304 + ko;
    qf[i] = *(const s16x8*)qp;
    kf[i] = *(const s16x8*)(qp + 256);
  }

#pragma unroll
  for (int it = 0; it < 2; ++it) {
    int slot = it * 64 + lane;
    int g = slot >> 2, s = slot & 3;
    if (g < 27) {
      u16x8 v = *(const u16x8*)(base + (size_t)g * 2304 + 512 + s * 8);
#pragma unroll
      for (int j = 0; j < 8; ++j) vt[(s * 8 + j) * LS + g] = v[j];
    } else {
#pragma unroll
      for (int j = 0; j < 8; ++j) vt[(s * 8 + j) * LS + g] = 0;
    }
  }

  f32x4 sacc[2][2];
#pragma unroll
  for (int i = 0; i < 2; ++i)
#pragma unroll
    for (int j = 0; j < 2; ++j) sacc[i][j] = (f32x4)0.f;
#pragma unroll
  for (int i = 0; i < 2; ++i)
#pragma unroll
    for (int j = 0; j < 2; ++j)
      sacc[i][j] = __builtin_amdgcn_mfma_f32_16x16x32_bf16(qf[i], kf[j], sacc[i][j], 0, 0, 0);

  const float scale = 0.17677669529663687f;
  const bool v1 = fr < 11;
#pragma unroll
  for (int i = 0; i < 2; ++i) {
#pragma unroll
    for (int r = 0; r < 4; ++r) {
      float a0 = sacc[i][0][r] * scale;
      float a1 = v1 ? sacc[i][1][r] * scale : -3.0e38f;
      float mx = fmaxf(a0, a1);
#pragma unroll
      for (int off = 1; off <= 8; off <<= 1) mx = fmaxf(mx, __shfl_xor(mx, off));
      float e0 = __expf(a0 - mx);
      float e1 = v1 ? __expf(a1 - mx) : 0.f;
      float sm = e0 + e1;
#pragma unroll
      for (int off = 1; off <= 8; off <<= 1) sm += __shfl_xor(sm, off);
      float inv = 1.f / sm;
      int row = i * 16 + 4 * g4 + r;
      pl[row * LS + fr] = f2bf(e0 * inv);
      pl[row * LS + 16 + fr] = f2bf(e1 * inv);
    }
  }
  __syncthreads();

  s16x8 pf[2], vf[2];
#pragma unroll
  for (int i = 0; i < 2; ++i) pf[i] = *(const s16x8*)&pl[(fr + 16 * i) * LS + ko];
#pragma unroll
  for (int j = 0; j < 2; ++j) vf[j] = *(const s16x8*)&vt[(fr + 16 * j) * LS + ko];

  f32x4 oacc[2][2];
#pragma unroll
  for (int i = 0; i < 2; ++i)
#pragma unroll
    for (int j = 0; j < 2; ++j) oacc[i][j] = (f32x4)0.f;
#pragma unroll
  for (int i = 0; i < 2; ++i)
#pragma unroll
    for (int j = 0; j < 2; ++j)
      oacc[i][j] = __builtin_amdgcn_mfma_f32_16x16x32_bf16(pf[i], vf[j], oacc[i][j], 0, 0, 0);

  __syncthreads();
#pragma unroll
  for (int i = 0; i < 2; ++i)
#pragma unroll
    for (int j = 0; j < 2; ++j)
#pragma unroll
      for (int r = 0; r < 4; ++r)
        vt[(i * 16 + 4 * g4 + r) * LS + j * 16 + fr] = f2bf(oacc[i][j][r]);
  __syncthreads();

#pragma unroll
  for (int it = 0; it < 2; ++it) {
    int slot = it * 64 + lane;
    int g = slot >> 2, s = slot & 3;
    if (g < 27) {
      u16x8 v = *(const u16x8*)&vt[g * LS + s * 8];
      *(u16x8*)(o + (size_t)(b * 81 + m + 3 * g) * 256 + hh * 32 + s * 8) = v;
    }
  }
}

__global__ __launch_bounds__(256) void cvt_kernel(const f32x4* __restrict__ src,
                                                  u16x4* __restrict__ dst, int n4) {
  int i = blockIdx.x * 256 + threadIdx.x;
  if (i < n4) {
    f32x4 v = src[i];
    u16x4 o;
#pragma unroll
    for (int j = 0; j < 4; ++j) o[j] = f2bf(v[j]);
    dst[i] = o;
  }
}

__global__ __launch_bounds__(256) void qkvpack_kernel(const float* __restrict__ Wq,
                                                      const float* __restrict__ Wk,
                                                      const float* __restrict__ Wv,
                                                      u16x4* __restrict__ dst) {
  int i4 = blockIdx.x * 256 + threadIdx.x;
  int e = i4 * 4;
  int l = e / 196608;
  int r = (e / 256) % 768;
  int c = e & 255;
  const float* src;
  if (r < 256) src = Wq + (size_t)l * 65536 + r * 256 + c;
  else if (r < 512) src = Wk + (size_t)l * 65536 + (r - 256) * 256 + c;
  else src = Wv + (size_t)l * 65536 + (r - 512) * 256 + c;
  f32x4 v = *(const f32x4*)src;
  u16x4 o;
#pragma unroll
  for (int j = 0; j < 4; ++j) o[j] = f2bf(v[j]);
  dst[i4] = o;
}

__global__ __launch_bounds__(256) void biaspack_kernel(const float* __restrict__ bq,
                                                       const float* __restrict__ bk,
                                                       const float* __restrict__ bv,
                                                       float* __restrict__ dst) {
  int i = blockIdx.x * 256 + threadIdx.x;
  if (i >= 2304) return;
  int l = i / 768, r = i % 768;
  float v = (r < 256) ? bq[l * 256 + r] : (r < 512) ? bk[l * 256 + r - 256]
                                                    : bv[l * 256 + r - 512];
  dst[i] = v;
}

extern "C" void kernel_launch(void* const* d_in, const int* in_sizes, int n_in,
                              void* d_out, int out_size, void* d_ws, size_t ws_size,
                              hipStream_t stream) {
  const float* x      = (const float*)d_in[0];
  const float* pos    = (const float*)d_in[1];
  const float* ln1_a  = (const float*)d_in[2];
  const float* ln1_b  = (const float*)d_in[3];
  const float* Wq     = (const float*)d_in[4];
  const float* bq     = (const float*)d_in[5];
  const float* Wk     = (const float*)d_in[6];
  const float* bk     = (const float*)d_in[7];
  const float* Wv     = (const float*)d_in[8];
  const float* bv     = (const float*)d_in[9];
  const float* Wo     = (const float*)d_in[10];
  const float* bo     = (const float*)d_in[11];
  const float* ln2_a  = (const float*)d_in[12];
  const float* ln2_b  = (const float*)d_in[13];
  const float* W1     = (const float*)d_in[14];
  const float* b1     = (const float*)d_in[15];
  const float* W2     = (const float*)d_in[16];
  const float* b2     = (const float*)d_in[17];
  const float* bn_g   = (const float*)d_in[18];
  const float* bn_b   = (const float*)d_in[19];
  const float* conv_w = (const float*)d_in[20];
  const float* conv_b = (const float*)d_in[21];

  char* ws = (char*)d_ws;
  unsigned short* xres = (unsigned short*)ws;  // bf16 residual stream
  unsigned short* bufA = (unsigned short*)(ws + 84934656);
  unsigned short* bufB = (unsigned short*)(ws + 127401984);
  unsigned short* wqkv3 = (unsigned short*)(ws + 254803968);
  unsigned short* wo3 = wqkv3 + 589824;
  unsigned short* w13 = wo3 + 196608;
  unsigned short* w23 = w13 + 393216;
  unsigned short* cw  = w23 + 393216;
  float* qkvb3 = (float*)(ws + 254803968 + 3171840);

  auto cvt = [&](const float* s, unsigned short* d, int n) {
    int n4 = n / 4;
    cvt_kernel<<<(n4 + 255) / 256, 256, 0, stream>>>((const f32x4*)s, (u16x4*)d, n4);
  };
  qkvpack_kernel<<<576, 256, 0, stream>>>(Wq, Wk, Wv, (u16x4*)wqkv3);
  biaspack_kernel<<<9, 256, 0, stream>>>(bq, bk, bv, qkvb3);
  cvt(Wo, wo3, 196608);
  cvt(W1, w13, 393216);
  cvt(W2, w23, 393216);
  cvt(conv_w, cw, 13056);

  addpos_ln<<<20736, 256, 0, stream>>>((const f32x4*)x, (const f32x4*)pos, ln1_a, ln1_b,
                                       xres, bufA);

  for (int l = 0; l < 3; ++l) {
    // fused QKV -> bufB [BT,768]
    gemm8<0, 3><<<1944, 512, 0, stream>>>(bufA, wqkv3 + l * 196608, qkvb3 + l * 768,
                                          (void*)bufB, 256, 768);
    attn_mfma<<<6144, 256, 0, stream>>>(bufB, bufA);
    // O-proj + resid(bf16) ; LN2 -> bufA
    gemm8ln<0><<<648, 512, 0, stream>>>(bufA, wo3 + l * 65536, bo + l * 256, xres,
                                        ln2_a + l * 256, ln2_b + l * 256, bufA, 256);
    // FFN1 (relu) -> bufB [BT,512]
    gemm8<1, 2><<<1296, 512, 0, stream>>>(bufA, w13 + l * 131072, b1 + l * 512,
                                          (void*)bufB, 256, 512);
    if (l < 2) {
      // FFN2 + resid(bf16) ; LN1(l+1) -> bufA
      gemm8ln<0><<<648, 512, 0, stream>>>(bufB, w23 + l * 131072, b2 + l * 256, xres,
                                          ln1_a + (l + 1) * 256, ln1_b + (l + 1) * 256,
                                          bufA, 512);
    } else {
      // FFN2 + resid ; BatchNorm -> bufA (xres not updated, dead)
      gemm8ln<1><<<648, 512, 0, stream>>>(bufB, w23 + l * 131072, b2 + l * 256, xres,
                                          bn_g, bn_b, bufA, 512);
    }
  }
  // final conv reads bf16 bufA -> d_out fp32
  gemm_cv<<<648, 256, 0, stream>>>(bufA, cw, conv_b, (float*)d_out);
}

// Round 11
// 731.714 us; speedup vs baseline: 1.6589x; 1.0488x over previous
//
#include <hip/hip_runtime.h>

// ---------------------------------------------------------------------------
// Transformer_16784732193201 — round 11
// vs r10: gemm8ln epilogue rebuilt as LDS-bounced + fully coalesced u16x8
// global I/O (was 192 scalar 2B ops/thread -> 24 vector 16B ops/thread).
// K-loop LDS reused as padded E[128][264] bf16 (union, 2 blk/CU).
// ws layout:
//   xres  bf16 [82944,256]               @ 0
//   bufA  bf16 [82944,256]               @ 84934656
//   bufB  bf16 [82944,768]               @ 127401984
//   weights bf16 + fused bias            @ 254803968
// ---------------------------------------------------------------------------

typedef __attribute__((ext_vector_type(4))) float f32x4;
typedef __attribute__((ext_vector_type(8))) short s16x8;
typedef __attribute__((ext_vector_type(4))) unsigned short u16x4;
typedef __attribute__((ext_vector_type(8))) unsigned short u16x8;

__device__ __forceinline__ float bf2f(unsigned short u) {
  unsigned int v = ((unsigned int)u) << 16;
  return __builtin_bit_cast(float, v);
}
__device__ __forceinline__ unsigned short f2bf(float f) {
  unsigned int u = __builtin_bit_cast(unsigned int, f);
  u += 0x7fffu + ((u >> 16) & 1u);
  return (unsigned short)(u >> 16);
}

#define GLD16(gp, lp)                                                       \
  __builtin_amdgcn_global_load_lds(                                         \
      (const __attribute__((address_space(1))) void*)(gp),                  \
      (__attribute__((address_space(3))) void*)(lp), 16, 0, 0)

// ---------------------------------------------------------------------------
// 8-wave GEMM: BM=128, BN=256, 512 threads (2x4 waves), single-buffer 48KB.
// EPI 0: bias -> bf16 ; 1: bias+relu -> bf16.
// ---------------------------------------------------------------------------
template <int EPI, int NY>
__global__ __launch_bounds__(512) void gemm8(
    const unsigned short* __restrict__ A, const unsigned short* __restrict__ W,
    const float* __restrict__ bias, void* __restrict__ Cout, int K, int ldc) {
  __shared__ unsigned short Alds[128 * 64];
  __shared__ unsigned short Blds[256 * 64];
  const int tid = threadIdx.x, wave = tid >> 6, lane = tid & 63;
  const int nwg = gridDim.x;
  const int swz = (blockIdx.x & 7) * (nwg >> 3) + (blockIdx.x >> 3);
  const int row0 = (swz / NY) * 128, ncol0 = (swz % NY) * 256;
  const int wr = wave >> 2, wc = wave & 3;
  const int fr = lane & 15, g4 = lane >> 4, ko = g4 * 8;
  const int swr = (fr & 7) << 3;
  const int l8 = lane >> 3;
  const int lkS = ((lane & 7) ^ l8) * 8;

  f32x4 acc[4][4];
#pragma unroll
  for (int i = 0; i < 4; ++i)
#pragma unroll
    for (int j = 0; j < 4; ++j) acc[i][j] = (f32x4)0.f;

  const int nkt = K / 64;
  for (int kt = 0; kt < nkt; ++kt) {
    __syncthreads();
#pragma unroll
    for (int j = 0; j < 2; ++j) {
      int ci = wave * 2 + j;
      const unsigned short* src = A + (size_t)(row0 + ci * 8 + l8) * K + kt * 64 + lkS;
      GLD16(src, &Alds[ci * 512]);
    }
#pragma unroll
    for (int j = 0; j < 4; ++j) {
      int ci = wave * 4 + j;
      const unsigned short* src = W + (size_t)(ncol0 + ci * 8 + l8) * K + kt * 64 + lkS;
      GLD16(src, &Blds[ci * 512]);
    }
    __syncthreads();
#pragma unroll
    for (int kk = 0; kk < 2; ++kk) {
      s16x8 af[4], bfr[4];
#pragma unroll
      for (int i = 0; i < 4; ++i)
        af[i] = *(const s16x8*)&Alds[(wr * 64 + i * 16 + fr) * 64 + ((kk * 32 + ko) ^ swr)];
#pragma unroll
      for (int j = 0; j < 4; ++j)
        bfr[j] = *(const s16x8*)&Blds[(wc * 64 + j * 16 + fr) * 64 + ((kk * 32 + ko) ^ swr)];
#pragma unroll
      for (int i = 0; i < 4; ++i)
#pragma unroll
        for (int j = 0; j < 4; ++j)
          acc[i][j] =
              __builtin_amdgcn_mfma_f32_16x16x32_bf16(af[i], bfr[j], acc[i][j], 0, 0, 0);
    }
  }

  const int cr = g4 * 4;
#pragma unroll
  for (int i = 0; i < 4; ++i) {
#pragma unroll
    for (int j = 0; j < 4; ++j) {
      int col = ncol0 + wc * 64 + j * 16 + fr;
      float bv = bias[col];
#pragma unroll
      for (int r = 0; r < 4; ++r) {
        int row = row0 + wr * 64 + i * 16 + cr + r;
        float v = acc[i][j][r] + bv;
        if constexpr (EPI == 1) v = fmaxf(v, 0.f);
        ((unsigned short*)Cout)[(size_t)row * ldc + col] = f2bf(v);
      }
    }
  }
}

// ---------------------------------------------------------------------------
// Full-row GEMM + bf16 residual + fused norm, LDS-bounced coalesced epilogue.
// BM=128, BN=256=N, NY=1.  v = acc + bias + xres;
// MODE 0 (LayerNorm): xres<-bf16(v); lnout = sa*(v-mean)/(sqrt(var)+eps)+sb
// MODE 1 (BatchNorm): lnout = v*is*sa+sb only (xres not updated, dead).
// Epilogue: (1) xres->E coalesced u16x8; (2) fragment add+stats in LDS;
// (3) coalesced writeback xres<-E and lnout<-norm(E).
// ---------------------------------------------------------------------------
template <int MODE>
__global__ __launch_bounds__(512) void gemm8ln(
    const unsigned short* __restrict__ A, const unsigned short* __restrict__ W,
    const float* __restrict__ bias, unsigned short* __restrict__ xres,
    const float* __restrict__ sa, const float* __restrict__ sb,
    unsigned short* __restrict__ lnout, int K) {
  constexpr int ES = 264;                  // padded row stride (shorts)
  __shared__ unsigned short SM[128 * ES];  // union: K-loop A|B tiles / E
  __shared__ float redS[128][4];
  __shared__ float redQ[128][4];
  unsigned short* Alds = SM;
  unsigned short* Blds = SM + 128 * 64;

  const int tid = threadIdx.x, wave = tid >> 6, lane = tid & 63;
  const int nwg = gridDim.x;
  const int swz = (blockIdx.x & 7) * (nwg >> 3) + (blockIdx.x >> 3);
  const int row0 = swz * 128;
  const int wr = wave >> 2, wc = wave & 3;
  const int fr = lane & 15, g4 = lane >> 4, ko = g4 * 8;
  const int swr = (fr & 7) << 3;
  const int l8 = lane >> 3;
  const int lkS = ((lane & 7) ^ l8) * 8;

  f32x4 acc[4][4];
#pragma unroll
  for (int i = 0; i < 4; ++i)
#pragma unroll
    for (int j = 0; j < 4; ++j) acc[i][j] = (f32x4)0.f;

  const int nkt = K / 64;
  for (int kt = 0; kt < nkt; ++kt) {
    __syncthreads();
#pragma unroll
    for (int j = 0; j < 2; ++j) {
      int ci = wave * 2 + j;
      const unsigned short* src = A + (size_t)(row0 + ci * 8 + l8) * K + kt * 64 + lkS;
      GLD16(src, &Alds[ci * 512]);
    }
#pragma unroll
    for (int j = 0; j < 4; ++j) {
      int ci = wave * 4 + j;
      const unsigned short* src = W + (size_t)(ci * 8 + l8) * K + kt * 64 + lkS;
      GLD16(src, &Blds[ci * 512]);
    }
    __syncthreads();
#pragma unroll
    for (int kk = 0; kk < 2; ++kk) {
      s16x8 af[4], bfr[4];
#pragma unroll
      for (int i = 0; i < 4; ++i)
        af[i] = *(const s16x8*)&Alds[(wr * 64 + i * 16 + fr) * 64 + ((kk * 32 + ko) ^ swr)];
#pragma unroll
      for (int j = 0; j < 4; ++j)
        bfr[j] = *(const s16x8*)&Blds[(wc * 64 + j * 16 + fr) * 64 + ((kk * 32 + ko) ^ swr)];
#pragma unroll
      for (int i = 0; i < 4; ++i)
#pragma unroll
        for (int j = 0; j < 4; ++j)
          acc[i][j] =
              __builtin_amdgcn_mfma_f32_16x16x32_bf16(af[i], bfr[j], acc[i][j], 0, 0, 0);
    }
  }

  const int cr = g4 * 4;
  float bv[4];
#pragma unroll
  for (int j = 0; j < 4; ++j) bv[j] = bias[wc * 64 + j * 16 + fr];

  const int erow = tid >> 5;       // base row (0..15)
  const int ec8 = (tid & 31) * 8;  // fixed 16B col chunk

  __syncthreads();  // all K-loop LDS reads done; SM is reusable as E
  // (1) coalesced xres -> E
#pragma unroll
  for (int p = 0; p < 8; ++p) {
    int row = p * 16 + erow;
    *(u16x8*)&SM[row * ES + ec8] =
        *(const u16x8*)&xres[(size_t)(row0 + row) * 256 + ec8];
  }
  __syncthreads();
  // (2) fragment add + stats in fp32; v back to E as bf16
#pragma unroll
  for (int i = 0; i < 4; ++i) {
    float s4[4] = {0.f, 0.f, 0.f, 0.f};
    float q4[4] = {0.f, 0.f, 0.f, 0.f};
#pragma unroll
    for (int j = 0; j < 4; ++j) {
      int col = wc * 64 + j * 16 + fr;
#pragma unroll
      for (int r = 0; r < 4; ++r) {
        int rl = wr * 64 + i * 16 + cr + r;
        float v = acc[i][j][r] + bv[j] + bf2f(SM[rl * ES + col]);
        SM[rl * ES + col] = f2bf(v);
        s4[r] += v;
        q4[r] += v * v;
      }
    }
    if constexpr (MODE == 0) {
#pragma unroll
      for (int r = 0; r < 4; ++r) {
        float s = s4[r], q = q4[r];
#pragma unroll
        for (int off = 1; off <= 8; off <<= 1) {
          s += __shfl_xor(s, off);
          q += __shfl_xor(q, off);
        }
        if (fr == 0) {
          int rl = wr * 64 + i * 16 + cr + r;
          redS[rl][wc] = s;
          redQ[rl][wc] = q;
        }
      }
    }
  }
  __syncthreads();
  // (3) coalesced writeback + norm
  f32x4 sa0 = *(const f32x4*)(sa + ec8), sa1 = *(const f32x4*)(sa + ec8 + 4);
  f32x4 sb0 = *(const f32x4*)(sb + ec8), sb1 = *(const f32x4*)(sb + ec8 + 4);
  if constexpr (MODE == 1) {
    const float is = 0.9999950000374997f;  // 1/sqrt(1+1e-5)
    sa0 *= is;
    sa1 *= is;
  }
#pragma unroll
  for (int p = 0; p < 8; ++p) {
    int row = p * 16 + erow;
    u16x8 vb = *(const u16x8*)&SM[row * ES + ec8];
    u16x8 o;
    if constexpr (MODE == 0) {
      *(u16x8*)&xres[(size_t)(row0 + row) * 256 + ec8] = vb;
      float s = redS[row][0] + redS[row][1] + redS[row][2] + redS[row][3];
      float q = redQ[row][0] + redQ[row][1] + redQ[row][2] + redQ[row][3];
      float mean = s * (1.f / 256.f);
      float var = fmaxf(q - 256.f * mean * mean, 0.f) * (1.f / 255.f);
      float scl = 1.f / (sqrtf(var) + 1e-6f);
#pragma unroll
      for (int e = 0; e < 4; ++e) {
        o[e] = f2bf(sa0[e] * (bf2f(vb[e]) - mean) * scl + sb0[e]);
        o[e + 4] = f2bf(sa1[e] * (bf2f(vb[e + 4]) - mean) * scl + sb1[e]);
      }
    } else {
#pragma unroll
      for (int e = 0; e < 4; ++e) {
        o[e] = f2bf(bf2f(vb[e]) * sa0[e] + sb0[e]);
        o[e + 4] = f2bf(bf2f(vb[e + 4]) * sa1[e] + sb1[e]);
      }
    }
    *(u16x8*)&lnout[(size_t)(row0 + row) * 256 + ec8] = o;
  }
}

// ---------------------------------------------------------------------------
// Final 51-col conv: BM=128, BN=64 (clamped rows), 4 waves 2x2, bf16 in.
// ---------------------------------------------------------------------------
__global__ __launch_bounds__(256) void gemm_cv(
    const unsigned short* __restrict__ A, const unsigned short* __restrict__ W,
    const float* __restrict__ bias, float* __restrict__ out) {
  constexpr int BM = 128, BK = 64, BN = 64, WN = 32, FN = 2;
  __shared__ unsigned short Alds[BM * BK];
  __shared__ unsigned short Blds[BN * BK];
  const int tid = threadIdx.x, wave = tid >> 6, lane = tid & 63;
  const int nwg = gridDim.x;
  const int swz = (blockIdx.x & 7) * (nwg >> 3) + (blockIdx.x >> 3);
  const int row0 = swz * BM;
  const int wr = wave >> 1, wc = wave & 1;
  const int fr = lane & 15, g4 = lane >> 4, ko = g4 * 8;
  const int swr = (fr & 7) << 3;
  const int l8 = lane >> 3;
  const int lkS = ((lane & 7) ^ l8) * 8;

  f32x4 acc[4][FN];
#pragma unroll
  for (int i = 0; i < 4; ++i)
#pragma unroll
    for (int j = 0; j < FN; ++j) acc[i][j] = (f32x4)0.f;

  for (int kt = 0; kt < 4; ++kt) {
    __syncthreads();
#pragma unroll
    for (int j = 0; j < 4; ++j) {
      int ci = wave * 4 + j;
      const unsigned short* src = A + (size_t)(row0 + ci * 8 + l8) * 256 + kt * BK + lkS;
      GLD16(src, &Alds[ci * 512]);
    }
    {
      int ci = wave * 2;
      int brow = ci * 8 + l8;
      if (brow > 50) brow = 50;
      const unsigned short* src = W + (size_t)brow * 256 + kt * BK + lkS;
      GLD16(src, &Blds[ci * 512]);
      int brow2 = (ci + 1) * 8 + l8;
      if (brow2 > 50) brow2 = 50;
      const unsigned short* src2 = W + (size_t)brow2 * 256 + kt * BK + lkS;
      GLD16(src2, &Blds[(ci + 1) * 512]);
    }
    __syncthreads();
#pragma unroll
    for (int kk = 0; kk < 2; ++kk) {
      s16x8 af[4], bfr[FN];
#pragma unroll
      for (int i = 0; i < 4; ++i)
        af[i] = *(const s16x8*)&Alds[(wr * 64 + i * 16 + fr) * BK + ((kk * 32 + ko) ^ swr)];
#pragma unroll
      for (int j = 0; j < FN; ++j)
        bfr[j] = *(const s16x8*)&Blds[(wc * WN + j * 16 + fr) * BK + ((kk * 32 + ko) ^ swr)];
#pragma unroll
      for (int i = 0; i < 4; ++i)
#pragma unroll
        for (int j = 0; j < FN; ++j)
          acc[i][j] =
              __builtin_amdgcn_mfma_f32_16x16x32_bf16(af[i], bfr[j], acc[i][j], 0, 0, 0);
    }
  }

  const int cr = g4 * 4;
#pragma unroll
  for (int i = 0; i < 4; ++i) {
#pragma unroll
    for (int j = 0; j < FN; ++j) {
      int col = wc * WN + j * 16 + fr;
      if (col >= 51) continue;
      float bv = bias[col];
#pragma unroll
      for (int r = 0; r < 4; ++r) {
        int row = row0 + wr * 64 + i * 16 + cr + r;
        out[(size_t)row * 51 + col] = acc[i][j][r] + bv;
      }
    }
  }
}

// ---------------------------------------------------------------------------
// Fused x+pos -> xres (bf16) and LayerNorm -> bufA (bf16). 1 wave per row.
// ---------------------------------------------------------------------------
__global__ __launch_bounds__(256) void addpos_ln(const f32x4* __restrict__ x,
                                                 const f32x4* __restrict__ pos,
                                                 const float* __restrict__ a,
                                                 const float* __restrict__ b,
                                                 unsigned short* __restrict__ xres,
                                                 unsigned short* __restrict__ lnout) {
  const int wave = threadIdx.x >> 6, lane = threadIdx.x & 63;
  const size_t row = (size_t)blockIdx.x * 4 + wave;
  f32x4 v = x[row * 64 + lane] + pos[(row % 81) * 64 + lane];
  u16x4 xb;
#pragma unroll
  for (int j = 0; j < 4; ++j) xb[j] = f2bf(v[j]);
  *(u16x4*)(xres + row * 256 + lane * 4) = xb;
  float s = v[0] + v[1] + v[2] + v[3];
#pragma unroll
  for (int off = 32; off >= 1; off >>= 1) s += __shfl_xor(s, off);
  float mean = s * (1.f / 256.f);
  f32x4 d = v - mean;
  float sq = d[0] * d[0] + d[1] * d[1] + d[2] * d[2] + d[3] * d[3];
#pragma unroll
  for (int off = 32; off >= 1; off >>= 1) sq += __shfl_xor(sq, off);
  float var = sq * (1.f / 255.f);
  float scl = 1.f / (sqrtf(var) + 1e-6f);
  f32x4 av = *(const f32x4*)(a + lane * 4);
  f32x4 bv = *(const f32x4*)(b + lane * 4);
  u16x4 ob;
#pragma unroll
  for (int j = 0; j < 4; ++j) ob[j] = f2bf(av[j] * d[j] * scl + bv[j]);
  *(u16x4*)(lnout + row * 256 + lane * 4) = ob;
}

// ---------------------------------------------------------------------------
// MFMA strided sparse attention. 1 wave = 1 stream (b,h,m); 4 waves/block.
// ---------------------------------------------------------------------------
__global__ __launch_bounds__(256) void attn_mfma(const unsigned short* __restrict__ qkv,
                                                 unsigned short* __restrict__ o) {
  constexpr int LS = 40;
  const int wave = threadIdx.x >> 6, lane = threadIdx.x & 63;
  const int sid = blockIdx.x * 4 + wave;
  const int m = sid % 3, hh = (sid / 3) & 7, b = sid / 24;
  __shared__ unsigned short VtS[4][32 * LS];
  __shared__ unsigned short PlS[4][32 * LS];
  unsigned short* vt = VtS[wave];
  unsigned short* pl = PlS[wave];

  const unsigned short* base = qkv + (size_t)b * 81 * 768 + (size_t)m * 768 + hh * 32;
  const int fr = lane & 15;
  const int ko = (lane >> 4) * 8;
  const int g4 = lane >> 4;

  s16x8 qf[2], kf[2];
#pragma unroll
  for (int i = 0; i < 2; ++i) {
    int g = fr + 16 * i;
    if (g > 26) g = 26;
    const unsigned short* qp = base + (size_t)g * 2304 + ko;
    qf[i] = *(const s16x8*)qp;
    kf[i] = *(const s16x8*)(qp + 256);
  }

#pragma unroll
  for (int it = 0; it < 2; ++it) {
    int slot = it * 64 + lane;
    int g = slot >> 2, s = slot & 3;
    if (g < 27) {
      u16x8 v = *(const u16x8*)(base + (size_t)g * 2304 + 512 + s * 8);
#pragma unroll
      for (int j = 0; j < 8; ++j) vt[(s * 8 + j) * LS + g] = v[j];
    } else {
#pragma unroll
      for (int j = 0; j < 8; ++j) vt[(s * 8 + j) * LS + g] = 0;
    }
  }

  f32x4 sacc[2][2];
#pragma unroll
  for (int i = 0; i < 2; ++i)
#pragma unroll
    for (int j = 0; j < 2; ++j) sacc[i][j] = (f32x4)0.f;
#pragma unroll
  for (int i = 0; i < 2; ++i)
#pragma unroll
    for (int j = 0; j < 2; ++j)
      sacc[i][j] = __builtin_amdgcn_mfma_f32_16x16x32_bf16(qf[i], kf[j], sacc[i][j], 0, 0, 0);

  const float scale = 0.17677669529663687f;
  const bool v1 = fr < 11;
#pragma unroll
  for (int i = 0; i < 2; ++i) {
#pragma unroll
    for (int r = 0; r < 4; ++r) {
      float a0 = sacc[i][0][r] * scale;
      float a1 = v1 ? sacc[i][1][r] * scale : -3.0e38f;
      float mx = fmaxf(a0, a1);
#pragma unroll
      for (int off = 1; off <= 8; off <<= 1) mx = fmaxf(mx, __shfl_xor(mx, off));
      float e0 = __expf(a0 - mx);
      float e1 = v1 ? __expf(a1 - mx) : 0.f;
      float sm = e0 + e1;
#pragma unroll
      for (int off = 1; off <= 8; off <<= 1) sm += __shfl_xor(sm, off);
      float inv = 1.f / sm;
      int row = i * 16 + 4 * g4 + r;
      pl[row * LS + fr] = f2bf(e0 * inv);
      pl[row * LS + 16 + fr] = f2bf(e1 * inv);
    }
  }
  __syncthreads();

  s16x8 pf[2], vf[2];
#pragma unroll
  for (int i = 0; i < 2; ++i) pf[i] = *(const s16x8*)&pl[(fr + 16 * i) * LS + ko];
#pragma unroll
  for (int j = 0; j < 2; ++j) vf[j] = *(const s16x8*)&vt[(fr + 16 * j) * LS + ko];

  f32x4 oacc[2][2];
#pragma unroll
  for (int i = 0; i < 2; ++i)
#pragma unroll
    for (int j = 0; j < 2; ++j) oacc[i][j] = (f32x4)0.f;
#pragma unroll
  for (int i = 0; i < 2; ++i)
#pragma unroll
    for (int j = 0; j < 2; ++j)
      oacc[i][j] = __builtin_amdgcn_mfma_f32_16x16x32_bf16(pf[i], vf[j], oacc[i][j], 0, 0, 0);

  __syncthreads();
#pragma unroll
  for (int i = 0; i < 2; ++i)
#pragma unroll
    for (int j = 0; j < 2; ++j)
#pragma unroll
      for (int r = 0; r < 4; ++r)
        vt[(i * 16 + 4 * g4 + r) * LS + j * 16 + fr] = f2bf(oacc[i][j][r]);
  __syncthreads();

#pragma unroll
  for (int it = 0; it < 2; ++it) {
    int slot = it * 64 + lane;
    int g = slot >> 2, s = slot & 3;
    if (g < 27) {
      u16x8 v = *(const u16x8*)&vt[g * LS + s * 8];
      *(u16x8*)(o + (size_t)(b * 81 + m + 3 * g) * 256 + hh * 32 + s * 8) = v;
    }
  }
}

__global__ __launch_bounds__(256) void cvt_kernel(const f32x4* __restrict__ src,
                                                  u16x4* __restrict__ dst, int n4) {
  int i = blockIdx.x * 256 + threadIdx.x;
  if (i < n4) {
    f32x4 v = src[i];
    u16x4 o;
#pragma unroll
    for (int j = 0; j < 4; ++j) o[j] = f2bf(v[j]);
    dst[i] = o;
  }
}

__global__ __launch_bounds__(256) void qkvpack_kernel(const float* __restrict__ Wq,
                                                      const float* __restrict__ Wk,
                                                      const float* __restrict__ Wv,
                                                      u16x4* __restrict__ dst) {
  int i4 = blockIdx.x * 256 + threadIdx.x;
  int e = i4 * 4;
  int l = e / 196608;
  int r = (e / 256) % 768;
  int c = e & 255;
  const float* src;
  if (r < 256) src = Wq + (size_t)l * 65536 + r * 256 + c;
  else if (r < 512) src = Wk + (size_t)l * 65536 + (r - 256) * 256 + c;
  else src = Wv + (size_t)l * 65536 + (r - 512) * 256 + c;
  f32x4 v = *(const f32x4*)src;
  u16x4 o;
#pragma unroll
  for (int j = 0; j < 4; ++j) o[j] = f2bf(v[j]);
  dst[i4] = o;
}

__global__ __launch_bounds__(256) void biaspack_kernel(const float* __restrict__ bq,
                                                       const float* __restrict__ bk,
                                                       const float* __restrict__ bv,
                                                       float* __restrict__ dst) {
  int i = blockIdx.x * 256 + threadIdx.x;
  if (i >= 2304) return;
  int l = i / 768, r = i % 768;
  float v = (r < 256) ? bq[l * 256 + r] : (r < 512) ? bk[l * 256 + r - 256]
                                                    : bv[l * 256 + r - 512];
  dst[i] = v;
}

extern "C" void kernel_launch(void* const* d_in, const int* in_sizes, int n_in,
                              void* d_out, int out_size, void* d_ws, size_t ws_size,
                              hipStream_t stream) {
  const float* x      = (const float*)d_in[0];
  const float* pos    = (const float*)d_in[1];
  const float* ln1_a  = (const float*)d_in[2];
  const float* ln1_b  = (const float*)d_in[3];
  const float* Wq     = (const float*)d_in[4];
  const float* bq     = (const float*)d_in[5];
  const float* Wk     = (const float*)d_in[6];
  const float* bk     = (const float*)d_in[7];
  const float* Wv     = (const float*)d_in[8];
  const float* bv     = (const float*)d_in[9];
  const float* Wo     = (const float*)d_in[10];
  const float* bo     = (const float*)d_in[11];
  const float* ln2_a  = (const float*)d_in[12];
  const float* ln2_b  = (const float*)d_in[13];
  const float* W1     = (const float*)d_in[14];
  const float* b1     = (const float*)d_in[15];
  const float* W2     = (const float*)d_in[16];
  const float* b2     = (const float*)d_in[17];
  const float* bn_g   = (const float*)d_in[18];
  const float* bn_b   = (const float*)d_in[19];
  const float* conv_w = (const float*)d_in[20];
  const float* conv_b = (const float*)d_in[21];

  char* ws = (char*)d_ws;
  unsigned short* xres = (unsigned short*)ws;  // bf16 residual stream
  unsigned short* bufA = (unsigned short*)(ws + 84934656);
  unsigned short* bufB = (unsigned short*)(ws + 127401984);
  unsigned short* wqkv3 = (unsigned short*)(ws + 254803968);
  unsigned short* wo3 = wqkv3 + 589824;
  unsigned short* w13 = wo3 + 196608;
  unsigned short* w23 = w13 + 393216;
  unsigned short* cw  = w23 + 393216;
  float* qkvb3 = (float*)(ws + 254803968 + 3171840);

  auto cvt = [&](const float* s, unsigned short* d, int n) {
    int n4 = n / 4;
    cvt_kernel<<<(n4 + 255) / 256, 256, 0, stream>>>((const f32x4*)s, (u16x4*)d, n4);
  };
  qkvpack_kernel<<<576, 256, 0, stream>>>(Wq, Wk, Wv, (u16x4*)wqkv3);
  biaspack_kernel<<<9, 256, 0, stream>>>(bq, bk, bv, qkvb3);
  cvt(Wo, wo3, 196608);
  cvt(W1, w13, 393216);
  cvt(W2, w23, 393216);
  cvt(conv_w, cw, 13056);

  addpos_ln<<<20736, 256, 0, stream>>>((const f32x4*)x, (const f32x4*)pos, ln1_a, ln1_b,
                                       xres, bufA);

  for (int l = 0; l < 3; ++l) {
    // fused QKV -> bufB [BT,768]
    gemm8<0, 3><<<1944, 512, 0, stream>>>(bufA, wqkv3 + l * 196608, qkvb3 + l * 768,
                                          (void*)bufB, 256, 768);
    attn_mfma<<<6144, 256, 0, stream>>>(bufB, bufA);
    // O-proj + resid(bf16) ; LN2 -> bufA
    gemm8ln<0><<<648, 512, 0, stream>>>(bufA, wo3 + l * 65536, bo + l * 256, xres,
                                        ln2_a + l * 256, ln2_b + l * 256, bufA, 256);
    // FFN1 (relu) -> bufB [BT,512]
    gemm8<1, 2><<<1296, 512, 0, stream>>>(bufA, w13 + l * 131072, b1 + l * 512,
                                          (void*)bufB, 256, 512);
    if (l < 2) {
      // FFN2 + resid(bf16) ; LN1(l+1) -> bufA
      gemm8ln<0><<<648, 512, 0, stream>>>(bufB, w23 + l * 131072, b2 + l * 256, xres,
                                          ln1_a + (l + 1) * 256, ln1_b + (l + 1) * 256,
                                          bufA, 512);
    } else {
      // FFN2 + resid ; BatchNorm -> bufA (xres not updated, dead)
      gemm8ln<1><<<648, 512, 0, stream>>>(bufB, w23 + l * 131072, b2 + l * 256, xres,
                                          bn_g, bn_b, bufA, 512);
    }
  }
  // final conv reads bf16 bufA -> d_out fp32
  gemm_cv<<<648, 256, 0, stream>>>(bufA, cw, conv_b, (float*)d_out);
}